// Round 7
// baseline (625.608 us; speedup 1.0000x reference)
//
#include <hip/hip_runtime.h>

#define CH 128
#define OUTC 10
#define NB 256            // buckets (dst >> 9), only ceil(N/512) used
#define BCAP 10240        // per-bucket pair capacity (avg ~8192, >22 sigma margin)
#define PCHUNK 2048       // edges per partition block

typedef __attribute__((ext_vector_type(8))) short short8;
typedef __attribute__((ext_vector_type(4))) float f32x4;

// ---------------------------------------------------------------- helpers

__device__ inline unsigned short f2bf(float f) {
    unsigned u = __builtin_bit_cast(unsigned, f);
    u += 0x7fffu + ((u >> 16) & 1u);   // RNE
    return (unsigned short)(u >> 16);
}
__device__ inline float bflo(unsigned u) { return __builtin_bit_cast(float, u << 16); }
__device__ inline float bfhi(unsigned u) { return __builtin_bit_cast(float, u & 0xffff0000u); }

__device__ inline void acc8(float* a, const uint4& v) {
    a[0] += bflo(v.x); a[1] += bfhi(v.x);
    a[2] += bflo(v.y); a[3] += bfhi(v.y);
    a[4] += bflo(v.z); a[5] += bfhi(v.z);
    a[6] += bflo(v.w); a[7] += bfhi(v.w);
}

// ---------------------------------------------------------------- prep: x -> bf16 AND weights -> bf16 transposed

struct WPtrs { const float* s[6]; unsigned short* d[6]; };

__global__ void prep_kernel(const float4* __restrict__ x4, uint2* __restrict__ xb, int n4,
                            int nConvBlk, WPtrs p) {
    int tid = threadIdx.x;
    if ((int)blockIdx.x < nConvBlk) {
        int i = blockIdx.x * 256 + tid;
        if (i < n4) {
            float4 v = x4[i];
            uint2 o;
            o.x = (unsigned)f2bf(v.x) | ((unsigned)f2bf(v.y) << 16);
            o.y = (unsigned)f2bf(v.z) | ((unsigned)f2bf(v.w) << 16);
            xb[i] = o;
        }
    } else {
        int b = blockIdx.x - nConvBlk;   // 0..383
        int m = b >> 6;                   // matrix 0..5
        int i = (b & 63) * 256 + tid;     // 0..16383
        int k = i >> 7;
        int nn = i & 127;
        p.d[m][nn * CH + k] = f2bf(p.s[m][i]);
    }
}

// ---------------------------------------------------------------- CSR build, phase 1: partition edges into buckets
// pairs[b*BCAP + pos] = (dstLocal << 17) | src

__global__ void partition_kernel(const int* __restrict__ src, const int* __restrict__ dst,
                                 int* __restrict__ bucketCnt, unsigned* __restrict__ pairs, int E) {
    __shared__ int hist[NB];
    __shared__ int base[NB];
    __shared__ int cur[NB];
    int tid = threadIdx.x;       // 256
    int e0 = blockIdx.x * PCHUNK;

    hist[tid] = 0;
    __syncthreads();
    #pragma unroll
    for (int i = 0; i < PCHUNK / 256; ++i) {
        int e = e0 + tid + i * 256;
        if (e < E) atomicAdd(&hist[dst[e] >> 9], 1);
    }
    __syncthreads();
    {
        int c = hist[tid];
        base[tid] = (c > 0) ? atomicAdd(&bucketCnt[tid], c) : 0;
        cur[tid] = 0;
    }
    __syncthreads();
    #pragma unroll
    for (int i = 0; i < PCHUNK / 256; ++i) {
        int e = e0 + tid + i * 256;
        if (e < E) {
            int d = dst[e];
            int bkt = d >> 9;
            int p = base[bkt] + atomicAdd(&cur[bkt], 1);
            if (p < BCAP)
                pairs[bkt * BCAP + p] = ((unsigned)(d & 511) << 17) | (unsigned)src[e];
        }
    }
}

// ---------------------------------------------------------------- CSR build, phase 2 (self-scans bucket counts)

__launch_bounds__(256)
__global__ void build_csr_kernel(const unsigned* __restrict__ pairs, const int* __restrict__ bucketCnt,
                                 int* __restrict__ offs, int* __restrict__ csr, int N) {
    __shared__ int bsm[NB];
    __shared__ int ldeg[512];
    __shared__ int s0[512], s1[512];
    __shared__ int lexc[512];
    __shared__ int lcur[512];
    __shared__ int lcsr[BCAP];

    int b = blockIdx.x;
    int node0 = b << 9;
    if (node0 >= N) return;
    int nLocal = min(512, N - node0);
    int tid = threadIdx.x;   // 256

    // inclusive scan of all 256 bucket counts -> gbase for this block
    bsm[tid] = bucketCnt[tid];
    __syncthreads();
    for (int off = 1; off < NB; off <<= 1) {
        int t = (tid >= off) ? bsm[tid - off] : 0;
        __syncthreads();
        bsm[tid] += t;
        __syncthreads();
    }
    int cnt = min(bucketCnt[b], BCAP);
    int gbase = bsm[b] - bucketCnt[b];

    for (int i = tid; i < 512; i += 256) ldeg[i] = 0;
    __syncthreads();
    for (int i = tid; i < cnt; i += 256)
        atomicAdd(&ldeg[pairs[b * BCAP + i] >> 17], 1);
    __syncthreads();

    for (int i = tid; i < 512; i += 256) s0[i] = ldeg[i];
    __syncthreads();
    int* sp = s0; int* dp = s1;
    for (int off = 1; off < 512; off <<= 1) {
        for (int i = tid; i < 512; i += 256)
            dp[i] = sp[i] + ((i >= off) ? sp[i - off] : 0);
        __syncthreads();
        int* t = sp; sp = dp; dp = t;
    }
    for (int i = tid; i < 512; i += 256) {
        int ex = sp[i] - ldeg[i];
        lexc[i] = ex;
        lcur[i] = ex;
    }
    __syncthreads();

    for (int i = tid; i < cnt; i += 256) {
        unsigned w = pairs[b * BCAP + i];
        int ppos = atomicAdd(&lcur[w >> 17], 1);
        lcsr[ppos] = (int)(w & 0x1ffffu);
    }
    __syncthreads();

    for (int i = tid; i < cnt; i += 256) csr[gbase + i] = lcsr[i];
    for (int i = tid; i < nLocal; i += 256) offs[node0 + i] = gbase + lexc[i];
    if (tid == 0 && node0 + nLocal == N) offs[N] = gbase + cnt;
}

// ---------------------------------------------------------------- aggregation (bf16, 8-edge unroll)

template <int L>
__launch_bounds__(256, 8)
__global__ void aggregate_kernel(const uint4* __restrict__ h4, const int* __restrict__ offs,
                                 const int* __restrict__ csr, uint4* __restrict__ z4, int n) {
    int node = blockIdx.x * 16 + (threadIdx.x >> 4);
    int lane = threadIdx.x & 15;
    if (node >= n) return;
    int beg = offs[node], end = offs[node + 1];

    float a[8];
    {
        uint4 self = h4[node * 16 + lane];
        a[0] = bflo(self.x); a[1] = bfhi(self.x);
        a[2] = bflo(self.y); a[3] = bfhi(self.y);
        a[4] = bflo(self.z); a[5] = bfhi(self.z);
        a[6] = bflo(self.w); a[7] = bfhi(self.w);
    }
    int e = beg;
    for (; e + 8 <= end; e += 8) {
        int s0 = csr[e],     s1 = csr[e + 1], s2 = csr[e + 2], s3 = csr[e + 3];
        int s4 = csr[e + 4], s5 = csr[e + 5], s6 = csr[e + 6], s7 = csr[e + 7];
        uint4 v0 = h4[s0 * 16 + lane];
        uint4 v1 = h4[s1 * 16 + lane];
        uint4 v2 = h4[s2 * 16 + lane];
        uint4 v3 = h4[s3 * 16 + lane];
        uint4 v4 = h4[s4 * 16 + lane];
        uint4 v5 = h4[s5 * 16 + lane];
        uint4 v6 = h4[s6 * 16 + lane];
        uint4 v7 = h4[s7 * 16 + lane];
        acc8(a, v0); acc8(a, v1); acc8(a, v2); acc8(a, v3);
        acc8(a, v4); acc8(a, v5); acc8(a, v6); acc8(a, v7);
    }
    for (; e + 2 <= end; e += 2) {
        int s0 = csr[e], s1 = csr[e + 1];
        uint4 v0 = h4[s0 * 16 + lane];
        uint4 v1 = h4[s1 * 16 + lane];
        acc8(a, v0); acc8(a, v1);
    }
    if (e < end) {
        uint4 v = h4[csr[e] * 16 + lane];
        acc8(a, v);
    }
    uint4 o;
    o.x = (unsigned)f2bf(a[0]) | ((unsigned)f2bf(a[1]) << 16);
    o.y = (unsigned)f2bf(a[2]) | ((unsigned)f2bf(a[3]) << 16);
    o.z = (unsigned)f2bf(a[4]) | ((unsigned)f2bf(a[5]) << 16);
    o.w = (unsigned)f2bf(a[6]) | ((unsigned)f2bf(a[7]) << 16);
    z4[node * 16 + lane] = o;
}

// ---------------------------------------------------------------- MFMA MLP: 128 rows/block, 512 threads
// RELU: inter-layer relu on output. POOL: pool epilogue instead of h write.

#define PQ 136
#define BM 128

template <int L, int RELU, int POOL>
__launch_bounds__(512, 2)
__global__ void mlp_mfma_kernel(const unsigned short* __restrict__ z,
                                const unsigned short* __restrict__ w1t, const float* __restrict__ b1,
                                const unsigned short* __restrict__ w2t, const float* __restrict__ b2,
                                unsigned short* __restrict__ hout,
                                const int* __restrict__ batch, float* __restrict__ pooled,
                                int n) {
    __shared__ __align__(16) unsigned short zs[BM * PQ];   // 34.8 KB
    __shared__ __align__(16) unsigned short ws[CH * PQ];   // 34.8 KB

    int tid = threadIdx.x;
    int row0 = blockIdx.x * BM;
    int wv = tid >> 6;        // 0..7
    int lane = tid & 63;
    int lm = lane & 15;
    int lq = lane >> 4;

    for (int i = tid; i < BM * 16; i += 512) {
        int r = i >> 4, c = i & 15;
        int row = row0 + r;
        uint4 v = (row < n) ? ((const uint4*)z)[row * 16 + c] : make_uint4(0, 0, 0, 0);
        *(uint4*)((char*)zs + r * (PQ * 2) + c * 16) = v;
    }
    for (int i = tid; i < CH * 16; i += 512) {
        int r = i >> 4, c = i & 15;
        *(uint4*)((char*)ws + r * (PQ * 2) + c * 16) = ((const uint4*)w1t)[i];
    }
    __syncthreads();

    // ---- matmul 1: t = relu(z @ w1 + b1)
    f32x4 acc[8];
    #pragma unroll
    for (int nt = 0; nt < 8; ++nt) {
        float bv = b1[nt * 16 + lm];
        acc[nt] = (f32x4){bv, bv, bv, bv};
    }
    int arow = wv * 16 + lm;
    #pragma unroll
    for (int kb = 0; kb < CH; kb += 32) {
        short8 afr = *(const short8*)&zs[arow * PQ + kb + 8 * lq];
        #pragma unroll
        for (int nt = 0; nt < 8; ++nt) {
            short8 bfr = *(const short8*)&ws[(nt * 16 + lm) * PQ + kb + 8 * lq];
            acc[nt] = __builtin_amdgcn_mfma_f32_16x16x32_bf16(afr, bfr, acc[nt], 0, 0, 0);
        }
    }
    __syncthreads();

    // scatter t (relu'd, bf16) into zs; stage w2T into ws
    #pragma unroll
    for (int nt = 0; nt < 8; ++nt)
        #pragma unroll
        for (int r = 0; r < 4; ++r) {
            float v = fmaxf(acc[nt][r], 0.f);
            zs[(wv * 16 + lq * 4 + r) * PQ + nt * 16 + lm] = f2bf(v);
        }
    for (int i = tid; i < CH * 16; i += 512) {
        int r = i >> 4, c = i & 15;
        *(uint4*)((char*)ws + r * (PQ * 2) + c * 16) = ((const uint4*)w2t)[i];
    }
    __syncthreads();

    // ---- matmul 2: h = t @ w2 + b2  [+ relu]
    #pragma unroll
    for (int nt = 0; nt < 8; ++nt) {
        float bv = b2[nt * 16 + lm];
        acc[nt] = (f32x4){bv, bv, bv, bv};
    }
    #pragma unroll
    for (int kb = 0; kb < CH; kb += 32) {
        short8 afr = *(const short8*)&zs[arow * PQ + kb + 8 * lq];
        #pragma unroll
        for (int nt = 0; nt < 8; ++nt) {
            short8 bfr = *(const short8*)&ws[(nt * 16 + lm) * PQ + kb + 8 * lq];
            acc[nt] = __builtin_amdgcn_mfma_f32_16x16x32_bf16(afr, bfr, acc[nt], 0, 0, 0);
        }
    }
    __syncthreads();

    #pragma unroll
    for (int nt = 0; nt < 8; ++nt)
        #pragma unroll
        for (int r = 0; r < 4; ++r) {
            float v = acc[nt][r];
            if (RELU) v = fmaxf(v, 0.f);
            zs[(wv * 16 + lq * 4 + r) * PQ + nt * 16 + lm] = f2bf(v);
        }
    __syncthreads();

    if (!POOL) {
        for (int i = tid; i < BM * 16; i += 512) {
            int r = i >> 4, c = i & 15;
            int row = row0 + r;
            if (row < n)
                ((uint4*)hout)[row * 16 + c] = *(const uint4*)((char*)zs + r * (PQ * 2) + c * 16);
        }
    } else {
        // pool epilogue from LDS tile (batch sorted): thread = (col-pair, row-stripe)
        int c2 = tid & 63;      // uint column (ch 2*c2, 2*c2+1)
        int rs = tid >> 6;      // 0..7
        float a0 = 0.f, a1 = 0.f;
        int prevg = -1;
        #pragma unroll
        for (int i = 0; i < BM / 8; ++i) {
            int r = rs + 8 * i;
            int row = row0 + r;
            if (row >= n) break;
            int g = batch[row];
            if (g != prevg) {
                if (prevg >= 0) {
                    atomicAdd(&pooled[prevg * CH + 2 * c2], a0);
                    atomicAdd(&pooled[prevg * CH + 2 * c2 + 1], a1);
                }
                prevg = g; a0 = 0.f; a1 = 0.f;
            }
            unsigned v = *(const unsigned*)((char*)zs + r * (PQ * 2) + c2 * 4);
            a0 += bflo(v); a1 += bfhi(v);
        }
        if (prevg >= 0) {
            atomicAdd(&pooled[prevg * CH + 2 * c2], a0);
            atomicAdd(&pooled[prevg * CH + 2 * c2 + 1], a1);
        }
    }
}

// ---------------------------------------------------------------- final linear

__global__ void final_linear_kernel(const float* __restrict__ pooled, const float* __restrict__ lin_w,
                                    const float* __restrict__ lin_b, float* __restrict__ out) {
    int g = blockIdx.x;
    int tid = threadIdx.x;   // 128
    __shared__ float pl[CH];
    pl[tid] = pooled[g * CH + tid];
    __syncthreads();
    if (tid < OUTC) {
        float a = lin_b[tid];
        #pragma unroll 16
        for (int c = 0; c < CH; ++c) a = fmaf(pl[c], lin_w[c * OUTC + tid], a);
        out[g * OUTC + tid] = a;
    }
}

// ---------------------------------------------------------------- launch

static inline size_t aln(size_t x) { return (x + 255) & ~size_t(255); }

extern "C" void kernel_launch(void* const* d_in, const int* in_sizes, int n_in,
                              void* d_out, int out_size, void* d_ws, size_t ws_size,
                              hipStream_t stream) {
    const float* x      = (const float*)d_in[0];
    const int*   ei     = (const int*)d_in[1];
    const int*   batch  = (const int*)d_in[2];
    const float* w1[3]  = {(const float*)d_in[3], (const float*)d_in[7],  (const float*)d_in[11]};
    const float* b1[3]  = {(const float*)d_in[4], (const float*)d_in[8],  (const float*)d_in[12]};
    const float* w2[3]  = {(const float*)d_in[5], (const float*)d_in[9],  (const float*)d_in[13]};
    const float* b2[3]  = {(const float*)d_in[6], (const float*)d_in[10], (const float*)d_in[14]};
    const float* lin_w  = (const float*)d_in[15];
    const float* lin_b  = (const float*)d_in[16];
    float* out = (float*)d_out;

    int E = in_sizes[1] / 2;
    int N = in_sizes[2];
    int n_graphs = out_size / OUTC;
    const int* src = ei;
    const int* dst = ei + E;

    char* p = (char*)d_ws;
    int* bucketCnt  = (int*)p; p += aln(NB * 4);
    unsigned* pairs = (unsigned*)p; p += aln((size_t)NB * BCAP * 4);
    int* offs       = (int*)p; p += aln((size_t)(N + 1) * 4);
    int* csr        = (int*)p; p += aln((size_t)E * 4);
    unsigned short* xb = (unsigned short*)p; p += aln((size_t)N * CH * 2);
    unsigned short* zb = (unsigned short*)p; p += aln((size_t)N * CH * 2);
    unsigned short* hA = (unsigned short*)p; p += aln((size_t)N * CH * 2);
    unsigned short* hB = (unsigned short*)p; p += aln((size_t)N * CH * 2);
    float* pooled = (float*)p; p += aln((size_t)n_graphs * CH * 4);
    unsigned short* wt[6];
    for (int i = 0; i < 6; ++i) { wt[i] = (unsigned short*)p; p += aln((size_t)CH * CH * 2); }
    (void)ws_size; (void)n_in;

    // zero bucket counters + pooled accumulator up front
    hipMemsetAsync(bucketCnt, 0, NB * 4, stream);
    hipMemsetAsync(pooled, 0, (size_t)n_graphs * CH * 4, stream);

    // prep: convert x + transpose weights, one dispatch
    int n4 = N * CH / 4;
    int nConvBlk = (n4 + 255) / 256;
    WPtrs wp;
    for (int l = 0; l < 3; ++l) {
        wp.s[2 * l] = w1[l];     wp.d[2 * l] = wt[2 * l];
        wp.s[2 * l + 1] = w2[l]; wp.d[2 * l + 1] = wt[2 * l + 1];
    }
    prep_kernel<<<nConvBlk + 384, 256, 0, stream>>>((const float4*)x, (uint2*)xb, n4, nConvBlk, wp);

    // CSR build
    partition_kernel<<<(E + PCHUNK - 1) / PCHUNK, 256, 0, stream>>>(src, dst, bucketCnt, pairs, E);
    build_csr_kernel<<<NB, 256, 0, stream>>>(pairs, bucketCnt, offs, csr, N);

    int ablk = (N + 15) / 16;
    int mblk = (N + BM - 1) / BM;

    // layer 0
    aggregate_kernel<0><<<ablk, 256, 0, stream>>>((const uint4*)xb, offs, csr, (uint4*)zb, N);
    mlp_mfma_kernel<0, 1, 0><<<mblk, 512, 0, stream>>>(zb, wt[0], b1[0], wt[1], b2[0], hA, batch, pooled, N);
    // layer 1
    aggregate_kernel<1><<<ablk, 256, 0, stream>>>((const uint4*)hA, offs, csr, (uint4*)zb, N);
    mlp_mfma_kernel<1, 1, 0><<<mblk, 512, 0, stream>>>(zb, wt[2], b1[1], wt[3], b2[1], hB, batch, pooled, N);
    // layer 2 (+ fused pooling epilogue)
    aggregate_kernel<2><<<ablk, 256, 0, stream>>>((const uint4*)hB, offs, csr, (uint4*)zb, N);
    mlp_mfma_kernel<2, 0, 1><<<mblk, 512, 0, stream>>>(zb, wt[4], b1[2], wt[5], b2[2], hA, batch, pooled, N);

    final_linear_kernel<<<n_graphs, CH, 0, stream>>>(pooled, lin_w, lin_b, out);
}

// Round 8
// 474.360 us; speedup vs baseline: 1.3188x; 1.3188x over previous
//
#include <hip/hip_runtime.h>

#define CH 128
#define OUTC 10
#define NB 256            // buckets (dst >> 9), only ceil(N/512) used
#define BCAP 10240        // per-bucket pair capacity (avg ~8192, >22 sigma margin)
#define PCHUNK 2048       // edges per partition block

typedef __attribute__((ext_vector_type(8))) short short8;
typedef __attribute__((ext_vector_type(16))) float f32x16;

// ---------------------------------------------------------------- helpers

__device__ inline unsigned short f2bf(float f) {
    unsigned u = __builtin_bit_cast(unsigned, f);
    u += 0x7fffu + ((u >> 16) & 1u);   // RNE
    return (unsigned short)(u >> 16);
}
__device__ inline float bflo(unsigned u) { return __builtin_bit_cast(float, u << 16); }
__device__ inline float bfhi(unsigned u) { return __builtin_bit_cast(float, u & 0xffff0000u); }

__device__ inline void acc8(float* a, const uint4& v) {
    a[0] += bflo(v.x); a[1] += bfhi(v.x);
    a[2] += bflo(v.y); a[3] += bfhi(v.y);
    a[4] += bflo(v.z); a[5] += bfhi(v.z);
    a[6] += bflo(v.w); a[7] += bfhi(v.w);
}

// ---------------------------------------------------------------- prep: x -> bf16 AND weights -> bf16 transposed

struct WPtrs { const float* s[6]; unsigned short* d[6]; };

__global__ void prep_kernel(const float4* __restrict__ x4, uint2* __restrict__ xb, int n4,
                            int nConvBlk, WPtrs p) {
    int tid = threadIdx.x;
    if ((int)blockIdx.x < nConvBlk) {
        int i = blockIdx.x * 256 + tid;
        if (i < n4) {
            float4 v = x4[i];
            uint2 o;
            o.x = (unsigned)f2bf(v.x) | ((unsigned)f2bf(v.y) << 16);
            o.y = (unsigned)f2bf(v.z) | ((unsigned)f2bf(v.w) << 16);
            xb[i] = o;
        }
    } else {
        int b = blockIdx.x - nConvBlk;   // 0..383
        int m = b >> 6;                   // matrix 0..5
        int i = (b & 63) * 256 + tid;     // 0..16383
        int k = i >> 7;
        int nn = i & 127;
        p.d[m][nn * CH + k] = f2bf(p.s[m][i]);
    }
}

// ---------------------------------------------------------------- CSR build, phase 1: partition edges into buckets

__global__ void partition_kernel(const int* __restrict__ src, const int* __restrict__ dst,
                                 int* __restrict__ bucketCnt, unsigned* __restrict__ pairs, int E) {
    __shared__ int hist[NB];
    __shared__ int base[NB];
    __shared__ int cur[NB];
    int tid = threadIdx.x;       // 256
    int e0 = blockIdx.x * PCHUNK;

    hist[tid] = 0;
    __syncthreads();
    #pragma unroll
    for (int i = 0; i < PCHUNK / 256; ++i) {
        int e = e0 + tid + i * 256;
        if (e < E) atomicAdd(&hist[dst[e] >> 9], 1);
    }
    __syncthreads();
    {
        int c = hist[tid];
        base[tid] = (c > 0) ? atomicAdd(&bucketCnt[tid], c) : 0;
        cur[tid] = 0;
    }
    __syncthreads();
    #pragma unroll
    for (int i = 0; i < PCHUNK / 256; ++i) {
        int e = e0 + tid + i * 256;
        if (e < E) {
            int d = dst[e];
            int bkt = d >> 9;
            int p = base[bkt] + atomicAdd(&cur[bkt], 1);
            if (p < BCAP)
                pairs[bkt * BCAP + p] = ((unsigned)(d & 511) << 17) | (unsigned)src[e];
        }
    }
}

// ---------------------------------------------------------------- CSR build, phase 2 (self-scans bucket counts)

__launch_bounds__(256)
__global__ void build_csr_kernel(const unsigned* __restrict__ pairs, const int* __restrict__ bucketCnt,
                                 int* __restrict__ offs, int* __restrict__ csr, int N) {
    __shared__ int bsm[NB];
    __shared__ int ldeg[512];
    __shared__ int s0[512], s1[512];
    __shared__ int lexc[512];
    __shared__ int lcur[512];
    __shared__ int lcsr[BCAP];

    int b = blockIdx.x;
    int node0 = b << 9;
    if (node0 >= N) return;
    int nLocal = min(512, N - node0);
    int tid = threadIdx.x;   // 256

    bsm[tid] = bucketCnt[tid];
    __syncthreads();
    for (int off = 1; off < NB; off <<= 1) {
        int t = (tid >= off) ? bsm[tid - off] : 0;
        __syncthreads();
        bsm[tid] += t;
        __syncthreads();
    }
    int cnt = min(bucketCnt[b], BCAP);
    int gbase = bsm[b] - bucketCnt[b];

    for (int i = tid; i < 512; i += 256) ldeg[i] = 0;
    __syncthreads();
    for (int i = tid; i < cnt; i += 256)
        atomicAdd(&ldeg[pairs[b * BCAP + i] >> 17], 1);
    __syncthreads();

    for (int i = tid; i < 512; i += 256) s0[i] = ldeg[i];
    __syncthreads();
    int* sp = s0; int* dp = s1;
    for (int off = 1; off < 512; off <<= 1) {
        for (int i = tid; i < 512; i += 256)
            dp[i] = sp[i] + ((i >= off) ? sp[i - off] : 0);
        __syncthreads();
        int* t = sp; sp = dp; dp = t;
    }
    for (int i = tid; i < 512; i += 256) {
        int ex = sp[i] - ldeg[i];
        lexc[i] = ex;
        lcur[i] = ex;
    }
    __syncthreads();

    for (int i = tid; i < cnt; i += 256) {
        unsigned w = pairs[b * BCAP + i];
        int ppos = atomicAdd(&lcur[w >> 17], 1);
        lcsr[ppos] = (int)(w & 0x1ffffu);
    }
    __syncthreads();

    for (int i = tid; i < cnt; i += 256) csr[gbase + i] = lcsr[i];
    for (int i = tid; i < nLocal; i += 256) offs[node0 + i] = gbase + lexc[i];
    if (tid == 0 && node0 + nLocal == N) offs[N] = gbase + cnt;
}

// ---------------------------------------------------------------- aggregation (bf16, 4-edge unroll — R6 known-good form)

template <int L>
__global__ void aggregate_kernel(const uint4* __restrict__ h4, const int* __restrict__ offs,
                                 const int* __restrict__ csr, uint4* __restrict__ z4, int n) {
    int node = blockIdx.x * 16 + (threadIdx.x >> 4);
    int lane = threadIdx.x & 15;
    if (node >= n) return;
    int beg = offs[node], end = offs[node + 1];

    float a[8];
    {
        uint4 self = h4[node * 16 + lane];
        a[0] = bflo(self.x); a[1] = bfhi(self.x);
        a[2] = bflo(self.y); a[3] = bfhi(self.y);
        a[4] = bflo(self.z); a[5] = bfhi(self.z);
        a[6] = bflo(self.w); a[7] = bfhi(self.w);
    }
    int e = beg;
    for (; e + 4 <= end; e += 4) {
        int s0 = csr[e], s1 = csr[e + 1], s2 = csr[e + 2], s3 = csr[e + 3];
        uint4 v0 = h4[s0 * 16 + lane];
        uint4 v1 = h4[s1 * 16 + lane];
        uint4 v2 = h4[s2 * 16 + lane];
        uint4 v3 = h4[s3 * 16 + lane];
        acc8(a, v0); acc8(a, v1); acc8(a, v2); acc8(a, v3);
    }
    for (; e < end; ++e) {
        uint4 v = h4[csr[e] * 16 + lane];
        acc8(a, v);
    }
    uint4 o;
    o.x = (unsigned)f2bf(a[0]) | ((unsigned)f2bf(a[1]) << 16);
    o.y = (unsigned)f2bf(a[2]) | ((unsigned)f2bf(a[3]) << 16);
    o.z = (unsigned)f2bf(a[4]) | ((unsigned)f2bf(a[5]) << 16);
    o.w = (unsigned)f2bf(a[6]) | ((unsigned)f2bf(a[7]) << 16);
    z4[node * 16 + lane] = o;
}

// ---------------------------------------------------------------- MFMA MLP v2: 32x32x16, B-frags from global (L1-hot),
// zs is the only LDS buffer. 128 rows/block, 512 threads, 8 waves.
// wave wv: row-tile rt = wv>>1 (32 rows), col-tiles ct0 = (wv&1)*2 and ct0+1.

#define PQ 136
#define BM 128

template <int L, int RELU, int POOL>
__launch_bounds__(512, 4)
__global__ void mlp_mfma_kernel(const unsigned short* __restrict__ z,
                                const unsigned short* __restrict__ w1t, const float* __restrict__ b1,
                                const unsigned short* __restrict__ w2t, const float* __restrict__ b2,
                                unsigned short* __restrict__ hout,
                                const int* __restrict__ batch, float* __restrict__ pooled,
                                int n) {
    __shared__ __align__(16) unsigned short zs[BM * PQ];   // 34.8 KB

    int tid = threadIdx.x;
    int row0 = blockIdx.x * BM;
    int wv = tid >> 6;         // 0..7
    int lane = tid & 63;
    int l31 = lane & 31;
    int kh = lane >> 5;        // 0..1
    int rt = wv >> 1;          // 0..3
    int ct0 = (wv & 1) * 2;    // 0 or 2
    int arow = rt * 32 + l31;

    // stage z tile
    for (int i = tid; i < BM * 16; i += 512) {
        int r = i >> 4, c = i & 15;
        int row = row0 + r;
        uint4 v = (row < n) ? ((const uint4*)z)[row * 16 + c] : make_uint4(0, 0, 0, 0);
        *(uint4*)((char*)zs + r * (PQ * 2) + c * 16) = v;
    }
    __syncthreads();

    // ---- matmul 1: t = relu(z @ w1 + b1)
    f32x16 acc0, acc1;
    {
        float bv0 = b1[ct0 * 32 + l31];
        float bv1 = b1[(ct0 + 1) * 32 + l31];
        #pragma unroll
        for (int r = 0; r < 16; ++r) { acc0[r] = bv0; acc1[r] = bv1; }
    }
    #pragma unroll
    for (int k0 = 0; k0 < 8; ++k0) {
        short8 afr = *(const short8*)&zs[arow * PQ + k0 * 16 + kh * 8];
        short8 bf0 = *(const short8*)&w1t[(ct0 * 32 + l31) * CH + k0 * 16 + kh * 8];
        short8 bf1 = *(const short8*)&w1t[((ct0 + 1) * 32 + l31) * CH + k0 * 16 + kh * 8];
        acc0 = __builtin_amdgcn_mfma_f32_32x32x16_bf16(afr, bf0, acc0, 0, 0, 0);
        acc1 = __builtin_amdgcn_mfma_f32_32x32x16_bf16(afr, bf1, acc1, 0, 0, 0);
    }
    __syncthreads();

    // scatter t (relu'd, bf16) into zs: C layout row=(reg&3)+8*(reg>>2)+4*kh, col=l31
    #pragma unroll
    for (int reg = 0; reg < 16; ++reg) {
        int row = (reg & 3) + 8 * (reg >> 2) + 4 * kh;
        zs[(rt * 32 + row) * PQ + ct0 * 32 + l31] = f2bf(fmaxf(acc0[reg], 0.f));
        zs[(rt * 32 + row) * PQ + (ct0 + 1) * 32 + l31] = f2bf(fmaxf(acc1[reg], 0.f));
    }
    __syncthreads();

    // ---- matmul 2: h = t @ w2 + b2  [+ relu]
    {
        float bv0 = b2[ct0 * 32 + l31];
        float bv1 = b2[(ct0 + 1) * 32 + l31];
        #pragma unroll
        for (int r = 0; r < 16; ++r) { acc0[r] = bv0; acc1[r] = bv1; }
    }
    #pragma unroll
    for (int k0 = 0; k0 < 8; ++k0) {
        short8 afr = *(const short8*)&zs[arow * PQ + k0 * 16 + kh * 8];
        short8 bf0 = *(const short8*)&w2t[(ct0 * 32 + l31) * CH + k0 * 16 + kh * 8];
        short8 bf1 = *(const short8*)&w2t[((ct0 + 1) * 32 + l31) * CH + k0 * 16 + kh * 8];
        acc0 = __builtin_amdgcn_mfma_f32_32x32x16_bf16(afr, bf0, acc0, 0, 0, 0);
        acc1 = __builtin_amdgcn_mfma_f32_32x32x16_bf16(afr, bf1, acc1, 0, 0, 0);
    }
    __syncthreads();

    #pragma unroll
    for (int reg = 0; reg < 16; ++reg) {
        int row = (reg & 3) + 8 * (reg >> 2) + 4 * kh;
        float v0 = acc0[reg], v1 = acc1[reg];
        if (RELU) { v0 = fmaxf(v0, 0.f); v1 = fmaxf(v1, 0.f); }
        zs[(rt * 32 + row) * PQ + ct0 * 32 + l31] = f2bf(v0);
        zs[(rt * 32 + row) * PQ + (ct0 + 1) * 32 + l31] = f2bf(v1);
    }
    __syncthreads();

    if (!POOL) {
        for (int i = tid; i < BM * 16; i += 512) {
            int r = i >> 4, c = i & 15;
            int row = row0 + r;
            if (row < n)
                ((uint4*)hout)[row * 16 + c] = *(const uint4*)((char*)zs + r * (PQ * 2) + c * 16);
        }
    } else {
        // pool epilogue from LDS tile (batch sorted)
        int c2 = tid & 63;      // uint column (ch 2*c2, 2*c2+1)
        int rs = tid >> 6;      // 0..7
        float a0 = 0.f, a1 = 0.f;
        int prevg = -1;
        #pragma unroll
        for (int i = 0; i < BM / 8; ++i) {
            int r = rs + 8 * i;
            int row = row0 + r;
            if (row >= n) break;
            int g = batch[row];
            if (g != prevg) {
                if (prevg >= 0) {
                    atomicAdd(&pooled[prevg * CH + 2 * c2], a0);
                    atomicAdd(&pooled[prevg * CH + 2 * c2 + 1], a1);
                }
                prevg = g; a0 = 0.f; a1 = 0.f;
            }
            unsigned v = *(const unsigned*)((char*)zs + r * (PQ * 2) + c2 * 4);
            a0 += bflo(v); a1 += bfhi(v);
        }
        if (prevg >= 0) {
            atomicAdd(&pooled[prevg * CH + 2 * c2], a0);
            atomicAdd(&pooled[prevg * CH + 2 * c2 + 1], a1);
        }
    }
}

// ---------------------------------------------------------------- final linear

__global__ void final_linear_kernel(const float* __restrict__ pooled, const float* __restrict__ lin_w,
                                    const float* __restrict__ lin_b, float* __restrict__ out) {
    int g = blockIdx.x;
    int tid = threadIdx.x;   // 128
    __shared__ float pl[CH];
    pl[tid] = pooled[g * CH + tid];
    __syncthreads();
    if (tid < OUTC) {
        float a = lin_b[tid];
        #pragma unroll 16
        for (int c = 0; c < CH; ++c) a = fmaf(pl[c], lin_w[c * OUTC + tid], a);
        out[g * OUTC + tid] = a;
    }
}

// ---------------------------------------------------------------- launch

static inline size_t aln(size_t x) { return (x + 255) & ~size_t(255); }

extern "C" void kernel_launch(void* const* d_in, const int* in_sizes, int n_in,
                              void* d_out, int out_size, void* d_ws, size_t ws_size,
                              hipStream_t stream) {
    const float* x      = (const float*)d_in[0];
    const int*   ei     = (const int*)d_in[1];
    const int*   batch  = (const int*)d_in[2];
    const float* w1[3]  = {(const float*)d_in[3], (const float*)d_in[7],  (const float*)d_in[11]};
    const float* b1[3]  = {(const float*)d_in[4], (const float*)d_in[8],  (const float*)d_in[12]};
    const float* w2[3]  = {(const float*)d_in[5], (const float*)d_in[9],  (const float*)d_in[13]};
    const float* b2[3]  = {(const float*)d_in[6], (const float*)d_in[10], (const float*)d_in[14]};
    const float* lin_w  = (const float*)d_in[15];
    const float* lin_b  = (const float*)d_in[16];
    float* out = (float*)d_out;

    int E = in_sizes[1] / 2;
    int N = in_sizes[2];
    int n_graphs = out_size / OUTC;
    const int* src = ei;
    const int* dst = ei + E;

    char* p = (char*)d_ws;
    int* bucketCnt  = (int*)p; p += aln(NB * 4);
    unsigned* pairs = (unsigned*)p; p += aln((size_t)NB * BCAP * 4);
    int* offs       = (int*)p; p += aln((size_t)(N + 1) * 4);
    int* csr        = (int*)p; p += aln((size_t)E * 4);
    unsigned short* xb = (unsigned short*)p; p += aln((size_t)N * CH * 2);
    unsigned short* zb = (unsigned short*)p; p += aln((size_t)N * CH * 2);
    unsigned short* hA = (unsigned short*)p; p += aln((size_t)N * CH * 2);
    unsigned short* hB = (unsigned short*)p; p += aln((size_t)N * CH * 2);
    float* pooled = (float*)p; p += aln((size_t)n_graphs * CH * 4);
    unsigned short* wt[6];
    for (int i = 0; i < 6; ++i) { wt[i] = (unsigned short*)p; p += aln((size_t)CH * CH * 2); }
    (void)ws_size; (void)n_in;

    // zero bucket counters + pooled accumulator up front
    hipMemsetAsync(bucketCnt, 0, NB * 4, stream);
    hipMemsetAsync(pooled, 0, (size_t)n_graphs * CH * 4, stream);

    // prep: convert x + transpose weights, one dispatch
    int n4 = N * CH / 4;
    int nConvBlk = (n4 + 255) / 256;
    WPtrs wp;
    for (int l = 0; l < 3; ++l) {
        wp.s[2 * l] = w1[l];     wp.d[2 * l] = wt[2 * l];
        wp.s[2 * l + 1] = w2[l]; wp.d[2 * l + 1] = wt[2 * l + 1];
    }
    prep_kernel<<<nConvBlk + 384, 256, 0, stream>>>((const float4*)x, (uint2*)xb, n4, nConvBlk, wp);

    // CSR build
    partition_kernel<<<(E + PCHUNK - 1) / PCHUNK, 256, 0, stream>>>(src, dst, bucketCnt, pairs, E);
    build_csr_kernel<<<NB, 256, 0, stream>>>(pairs, bucketCnt, offs, csr, N);

    int ablk = (N + 15) / 16;
    int mblk = (N + BM - 1) / BM;

    // layer 0
    aggregate_kernel<0><<<ablk, 256, 0, stream>>>((const uint4*)xb, offs, csr, (uint4*)zb, N);
    mlp_mfma_kernel<0, 1, 0><<<mblk, 512, 0, stream>>>(zb, wt[0], b1[0], wt[1], b2[0], hA, batch, pooled, N);
    // layer 1
    aggregate_kernel<1><<<ablk, 256, 0, stream>>>((const uint4*)hA, offs, csr, (uint4*)zb, N);
    mlp_mfma_kernel<1, 1, 0><<<mblk, 512, 0, stream>>>(zb, wt[2], b1[1], wt[3], b2[1], hB, batch, pooled, N);
    // layer 2 (+ fused pooling epilogue)
    aggregate_kernel<2><<<ablk, 256, 0, stream>>>((const uint4*)hB, offs, csr, (uint4*)zb, N);
    mlp_mfma_kernel<2, 0, 1><<<mblk, 512, 0, stream>>>(zb, wt[4], b1[2], wt[5], b2[2], hA, batch, pooled, N);

    final_linear_kernel<<<n_graphs, CH, 0, stream>>>(pooled, lin_w, lin_b, out);
}

// Round 9
// 435.295 us; speedup vs baseline: 1.4372x; 1.0897x over previous
//
#include <hip/hip_runtime.h>

#define CH 128
#define OUTC 10
#define NB 256            // buckets (dst >> 9), only ceil(N/512) used
#define BCAP 10240        // per-bucket pair capacity (avg ~8192, >22 sigma margin)
#define PCHUNK 2048       // edges per partition block

typedef __attribute__((ext_vector_type(8))) short short8;
typedef __attribute__((ext_vector_type(4))) short short4v;
typedef __attribute__((ext_vector_type(16))) float f32x16;

// ---------------------------------------------------------------- helpers

__device__ inline unsigned short f2bf(float f) {
    unsigned u = __builtin_bit_cast(unsigned, f);
    u += 0x7fffu + ((u >> 16) & 1u);   // RNE
    return (unsigned short)(u >> 16);
}
__device__ inline float bflo(unsigned u) { return __builtin_bit_cast(float, u << 16); }
__device__ inline float bfhi(unsigned u) { return __builtin_bit_cast(float, u & 0xffff0000u); }

__device__ inline void acc8(float* a, const uint4& v) {
    a[0] += bflo(v.x); a[1] += bfhi(v.x);
    a[2] += bflo(v.y); a[3] += bfhi(v.y);
    a[4] += bflo(v.z); a[5] += bfhi(v.z);
    a[6] += bflo(v.w); a[7] += bfhi(v.w);
}

// ---------------------------------------------------------------- prep: x -> bf16 AND weights -> MFMA-fragment-swizzled bf16
// wsw element i (per matrix): j=i&7, l=(i>>3)&63, k0=(i>>9)&7, ct=(i>>12)&3
// stores w[(k0*16 + (l>>5)*8 + j)*128 + ct*32 + (l&31)]
// so that B-frag load for (ct,k0) is wsw + ((ct*8+k0)*64 + lane)*8 shorts — wave-contiguous.

struct WPtrs { const float* s[6]; unsigned short* d[6]; };

__global__ void prep_kernel(const float4* __restrict__ x4, uint2* __restrict__ xb, int n4,
                            int nConvBlk, WPtrs p) {
    int tid = threadIdx.x;
    if ((int)blockIdx.x < nConvBlk) {
        int i = blockIdx.x * 256 + tid;
        if (i < n4) {
            float4 v = x4[i];
            uint2 o;
            o.x = (unsigned)f2bf(v.x) | ((unsigned)f2bf(v.y) << 16);
            o.y = (unsigned)f2bf(v.z) | ((unsigned)f2bf(v.w) << 16);
            xb[i] = o;
        }
    } else {
        int b = blockIdx.x - nConvBlk;   // 0..383
        int m = b >> 6;                   // matrix 0..5
        int i = (b & 63) * 256 + tid;     // 0..16383
        int j = i & 7;
        int l = (i >> 3) & 63;
        int k0 = (i >> 9) & 7;
        int ct = (i >> 12) & 3;
        int k = k0 * 16 + ((l >> 5) << 3) + j;
        int nn = ct * 32 + (l & 31);
        p.d[m][i] = f2bf(p.s[m][k * CH + nn]);
    }
}

// ---------------------------------------------------------------- CSR build, phase 1: partition edges into buckets

__global__ void partition_kernel(const int* __restrict__ src, const int* __restrict__ dst,
                                 int* __restrict__ bucketCnt, unsigned* __restrict__ pairs, int E) {
    __shared__ int hist[NB];
    __shared__ int base[NB];
    __shared__ int cur[NB];
    int tid = threadIdx.x;       // 256
    int e0 = blockIdx.x * PCHUNK;

    hist[tid] = 0;
    __syncthreads();
    #pragma unroll
    for (int i = 0; i < PCHUNK / 256; ++i) {
        int e = e0 + tid + i * 256;
        if (e < E) atomicAdd(&hist[dst[e] >> 9], 1);
    }
    __syncthreads();
    {
        int c = hist[tid];
        base[tid] = (c > 0) ? atomicAdd(&bucketCnt[tid], c) : 0;
        cur[tid] = 0;
    }
    __syncthreads();
    #pragma unroll
    for (int i = 0; i < PCHUNK / 256; ++i) {
        int e = e0 + tid + i * 256;
        if (e < E) {
            int d = dst[e];
            int bkt = d >> 9;
            int p = base[bkt] + atomicAdd(&cur[bkt], 1);
            if (p < BCAP)
                pairs[bkt * BCAP + p] = ((unsigned)(d & 511) << 17) | (unsigned)src[e];
        }
    }
}

// ---------------------------------------------------------------- CSR build, phase 2 (self-scans bucket counts)

__launch_bounds__(256)
__global__ void build_csr_kernel(const unsigned* __restrict__ pairs, const int* __restrict__ bucketCnt,
                                 int* __restrict__ offs, int* __restrict__ csr, int N) {
    __shared__ int bsm[NB];
    __shared__ int ldeg[512];
    __shared__ int s0[512], s1[512];
    __shared__ int lexc[512];
    __shared__ int lcur[512];
    __shared__ int lcsr[BCAP];

    int b = blockIdx.x;
    int node0 = b << 9;
    if (node0 >= N) return;
    int nLocal = min(512, N - node0);
    int tid = threadIdx.x;   // 256

    bsm[tid] = bucketCnt[tid];
    __syncthreads();
    for (int off = 1; off < NB; off <<= 1) {
        int t = (tid >= off) ? bsm[tid - off] : 0;
        __syncthreads();
        bsm[tid] += t;
        __syncthreads();
    }
    int cnt = min(bucketCnt[b], BCAP);
    int gbase = bsm[b] - bucketCnt[b];

    for (int i = tid; i < 512; i += 256) ldeg[i] = 0;
    __syncthreads();
    for (int i = tid; i < cnt; i += 256)
        atomicAdd(&ldeg[pairs[b * BCAP + i] >> 17], 1);
    __syncthreads();

    for (int i = tid; i < 512; i += 256) s0[i] = ldeg[i];
    __syncthreads();
    int* sp = s0; int* dp = s1;
    for (int off = 1; off < 512; off <<= 1) {
        for (int i = tid; i < 512; i += 256)
            dp[i] = sp[i] + ((i >= off) ? sp[i - off] : 0);
        __syncthreads();
        int* t = sp; sp = dp; dp = t;
    }
    for (int i = tid; i < 512; i += 256) {
        int ex = sp[i] - ldeg[i];
        lexc[i] = ex;
        lcur[i] = ex;
    }
    __syncthreads();

    for (int i = tid; i < cnt; i += 256) {
        unsigned w = pairs[b * BCAP + i];
        int ppos = atomicAdd(&lcur[w >> 17], 1);
        lcsr[ppos] = (int)(w & 0x1ffffu);
    }
    __syncthreads();

    for (int i = tid; i < cnt; i += 256) csr[gbase + i] = lcsr[i];
    for (int i = tid; i < nLocal; i += 256) offs[node0 + i] = gbase + lexc[i];
    if (tid == 0 && node0 + nLocal == N) offs[N] = gbase + cnt;
}

// ---------------------------------------------------------------- aggregation (bf16, 4-edge unroll — known-good form)

template <int L>
__global__ void aggregate_kernel(const uint4* __restrict__ h4, const int* __restrict__ offs,
                                 const int* __restrict__ csr, uint4* __restrict__ z4, int n) {
    int node = blockIdx.x * 16 + (threadIdx.x >> 4);
    int lane = threadIdx.x & 15;
    if (node >= n) return;
    int beg = offs[node], end = offs[node + 1];

    float a[8];
    {
        uint4 self = h4[node * 16 + lane];
        a[0] = bflo(self.x); a[1] = bfhi(self.x);
        a[2] = bflo(self.y); a[3] = bfhi(self.y);
        a[4] = bflo(self.z); a[5] = bfhi(self.z);
        a[6] = bflo(self.w); a[7] = bfhi(self.w);
    }
    int e = beg;
    for (; e + 4 <= end; e += 4) {
        int s0 = csr[e], s1 = csr[e + 1], s2 = csr[e + 2], s3 = csr[e + 3];
        uint4 v0 = h4[s0 * 16 + lane];
        uint4 v1 = h4[s1 * 16 + lane];
        uint4 v2 = h4[s2 * 16 + lane];
        uint4 v3 = h4[s3 * 16 + lane];
        acc8(a, v0); acc8(a, v1); acc8(a, v2); acc8(a, v3);
    }
    for (; e < end; ++e) {
        uint4 v = h4[csr[e] * 16 + lane];
        acc8(a, v);
    }
    uint4 o;
    o.x = (unsigned)f2bf(a[0]) | ((unsigned)f2bf(a[1]) << 16);
    o.y = (unsigned)f2bf(a[2]) | ((unsigned)f2bf(a[3]) << 16);
    o.z = (unsigned)f2bf(a[4]) | ((unsigned)f2bf(a[5]) << 16);
    o.w = (unsigned)f2bf(a[6]) | ((unsigned)f2bf(a[7]) << 16);
    z4[node * 16 + lane] = o;
}

// ---------------------------------------------------------------- MFMA MLP v3: 32x32x16, fragment-swizzled B from global
// (wave-contiguous 1024 B loads, L1-hot), zs only LDS buffer, pitch 132 (2-way = free).
// 128 rows/block, 512 threads, 8 waves: wave = (rt = wv&3) x (ch = wv>>2 col-half).

#define PQ2 132
#define BM 128

template <int L, int RELU, int POOL>
__launch_bounds__(512)
__global__ void mlp_mfma_kernel(const unsigned short* __restrict__ z,
                                const unsigned short* __restrict__ w1s, const float* __restrict__ b1,
                                const unsigned short* __restrict__ w2s, const float* __restrict__ b2,
                                unsigned short* __restrict__ hout,
                                const int* __restrict__ batch, float* __restrict__ pooled,
                                int n) {
    __shared__ __align__(16) unsigned short zs[BM * PQ2];   // 33.8 KB

    int tid = threadIdx.x;
    int row0 = blockIdx.x * BM;
    int wv = tid >> 6;         // 0..7
    int lane = tid & 63;
    int l31 = lane & 31;
    int kh = lane >> 5;        // 0..1
    int rt = wv & 3;           // row tile (32 rows)
    int ch = wv >> 2;          // col half (64 cols)
    int ct0 = ch * 2;
    int arow = rt * 32 + l31;

    // stage z tile (8-B writes, pitch 132)
    for (int i = tid; i < BM * 16; i += 512) {
        int r = i >> 4, c = i & 15;
        int row = row0 + r;
        uint4 v = (row < n) ? ((const uint4*)z)[row * 16 + c] : make_uint4(0, 0, 0, 0);
        *(uint2*)&zs[r * PQ2 + c * 8]     = make_uint2(v.x, v.y);
        *(uint2*)&zs[r * PQ2 + c * 8 + 4] = make_uint2(v.z, v.w);
    }
    __syncthreads();

    // ---- matmul 1: t = relu(z @ w1 + b1)
    f32x16 acc0, acc1;
    {
        float bv0 = b1[ct0 * 32 + l31];
        float bv1 = b1[(ct0 + 1) * 32 + l31];
        #pragma unroll
        for (int r = 0; r < 16; ++r) { acc0[r] = bv0; acc1[r] = bv1; }
    }
    #pragma unroll
    for (int k0 = 0; k0 < 8; ++k0) {
        short8 afr;
        {
            short4v lo = *(const short4v*)&zs[arow * PQ2 + k0 * 16 + kh * 8];
            short4v hi = *(const short4v*)&zs[arow * PQ2 + k0 * 16 + kh * 8 + 4];
            afr = (short8){lo[0], lo[1], lo[2], lo[3], hi[0], hi[1], hi[2], hi[3]};
        }
        short8 bf0 = *(const short8*)&w1s[(((ct0 * 8 + k0) * 64) + lane) * 8];
        short8 bf1 = *(const short8*)&w1s[((((ct0 + 1) * 8 + k0) * 64) + lane) * 8];
        acc0 = __builtin_amdgcn_mfma_f32_32x32x16_bf16(afr, bf0, acc0, 0, 0, 0);
        acc1 = __builtin_amdgcn_mfma_f32_32x32x16_bf16(afr, bf1, acc1, 0, 0, 0);
    }
    __syncthreads();

    // scatter t (relu'd, bf16) into zs: C layout row=(reg&3)+8*(reg>>2)+4*kh, col=l31
    #pragma unroll
    for (int reg = 0; reg < 16; ++reg) {
        int crow = (reg & 3) + 8 * (reg >> 2) + 4 * kh;
        zs[(rt * 32 + crow) * PQ2 + ch * 64 + l31]      = f2bf(fmaxf(acc0[reg], 0.f));
        zs[(rt * 32 + crow) * PQ2 + ch * 64 + 32 + l31] = f2bf(fmaxf(acc1[reg], 0.f));
    }
    __syncthreads();

    // ---- matmul 2: h = t @ w2 + b2  [+ relu]
    {
        float bv0 = b2[ct0 * 32 + l31];
        float bv1 = b2[(ct0 + 1) * 32 + l31];
        #pragma unroll
        for (int r = 0; r < 16; ++r) { acc0[r] = bv0; acc1[r] = bv1; }
    }
    #pragma unroll
    for (int k0 = 0; k0 < 8; ++k0) {
        short8 afr;
        {
            short4v lo = *(const short4v*)&zs[arow * PQ2 + k0 * 16 + kh * 8];
            short4v hi = *(const short4v*)&zs[arow * PQ2 + k0 * 16 + kh * 8 + 4];
            afr = (short8){lo[0], lo[1], lo[2], lo[3], hi[0], hi[1], hi[2], hi[3]};
        }
        short8 bf0 = *(const short8*)&w2s[(((ct0 * 8 + k0) * 64) + lane) * 8];
        short8 bf1 = *(const short8*)&w2s[((((ct0 + 1) * 8 + k0) * 64) + lane) * 8];
        acc0 = __builtin_amdgcn_mfma_f32_32x32x16_bf16(afr, bf0, acc0, 0, 0, 0);
        acc1 = __builtin_amdgcn_mfma_f32_32x32x16_bf16(afr, bf1, acc1, 0, 0, 0);
    }
    __syncthreads();

    #pragma unroll
    for (int reg = 0; reg < 16; ++reg) {
        int crow = (reg & 3) + 8 * (reg >> 2) + 4 * kh;
        float v0 = acc0[reg], v1 = acc1[reg];
        if (RELU) { v0 = fmaxf(v0, 0.f); v1 = fmaxf(v1, 0.f); }
        zs[(rt * 32 + crow) * PQ2 + ch * 64 + l31]      = f2bf(v0);
        zs[(rt * 32 + crow) * PQ2 + ch * 64 + 32 + l31] = f2bf(v1);
    }
    __syncthreads();

    if (!POOL) {
        for (int i = tid; i < BM * 16; i += 512) {
            int r = i >> 4, c = i & 15;
            int row = row0 + r;
            if (row < n) {
                uint2 a = *(const uint2*)&zs[r * PQ2 + c * 8];
                uint2 b = *(const uint2*)&zs[r * PQ2 + c * 8 + 4];
                ((uint4*)hout)[row * 16 + c] = make_uint4(a.x, a.y, b.x, b.y);
            }
        }
    } else {
        // pool epilogue from LDS tile (batch sorted)
        int c2 = tid & 63;      // uint column (ch 2*c2, 2*c2+1)
        int rs = tid >> 6;      // 0..7
        float a0 = 0.f, a1 = 0.f;
        int prevg = -1;
        #pragma unroll
        for (int i = 0; i < BM / 8; ++i) {
            int r = rs + 8 * i;
            int row = row0 + r;
            if (row >= n) break;
            int g = batch[row];
            if (g != prevg) {
                if (prevg >= 0) {
                    atomicAdd(&pooled[prevg * CH + 2 * c2], a0);
                    atomicAdd(&pooled[prevg * CH + 2 * c2 + 1], a1);
                }
                prevg = g; a0 = 0.f; a1 = 0.f;
            }
            unsigned v = *(const unsigned*)&zs[r * PQ2 + c2 * 2];
            a0 += bflo(v); a1 += bfhi(v);
        }
        if (prevg >= 0) {
            atomicAdd(&pooled[prevg * CH + 2 * c2], a0);
            atomicAdd(&pooled[prevg * CH + 2 * c2 + 1], a1);
        }
    }
}

// ---------------------------------------------------------------- final linear

__global__ void final_linear_kernel(const float* __restrict__ pooled, const float* __restrict__ lin_w,
                                    const float* __restrict__ lin_b, float* __restrict__ out) {
    int g = blockIdx.x;
    int tid = threadIdx.x;   // 128
    __shared__ float pl[CH];
    pl[tid] = pooled[g * CH + tid];
    __syncthreads();
    if (tid < OUTC) {
        float a = lin_b[tid];
        #pragma unroll 16
        for (int c = 0; c < CH; ++c) a = fmaf(pl[c], lin_w[c * OUTC + tid], a);
        out[g * OUTC + tid] = a;
    }
}

// ---------------------------------------------------------------- launch

static inline size_t aln(size_t x) { return (x + 255) & ~size_t(255); }

extern "C" void kernel_launch(void* const* d_in, const int* in_sizes, int n_in,
                              void* d_out, int out_size, void* d_ws, size_t ws_size,
                              hipStream_t stream) {
    const float* x      = (const float*)d_in[0];
    const int*   ei     = (const int*)d_in[1];
    const int*   batch  = (const int*)d_in[2];
    const float* w1[3]  = {(const float*)d_in[3], (const float*)d_in[7],  (const float*)d_in[11]};
    const float* b1[3]  = {(const float*)d_in[4], (const float*)d_in[8],  (const float*)d_in[12]};
    const float* w2[3]  = {(const float*)d_in[5], (const float*)d_in[9],  (const float*)d_in[13]};
    const float* b2[3]  = {(const float*)d_in[6], (const float*)d_in[10], (const float*)d_in[14]};
    const float* lin_w  = (const float*)d_in[15];
    const float* lin_b  = (const float*)d_in[16];
    float* out = (float*)d_out;

    int E = in_sizes[1] / 2;
    int N = in_sizes[2];
    int n_graphs = out_size / OUTC;
    const int* src = ei;
    const int* dst = ei + E;

    char* p = (char*)d_ws;
    int* bucketCnt  = (int*)p; p += aln(NB * 4);
    unsigned* pairs = (unsigned*)p; p += aln((size_t)NB * BCAP * 4);
    int* offs       = (int*)p; p += aln((size_t)(N + 1) * 4);
    int* csr        = (int*)p; p += aln((size_t)E * 4);
    unsigned short* xb = (unsigned short*)p; p += aln((size_t)N * CH * 2);
    unsigned short* zb = (unsigned short*)p; p += aln((size_t)N * CH * 2);
    unsigned short* hA = (unsigned short*)p; p += aln((size_t)N * CH * 2);
    unsigned short* hB = (unsigned short*)p; p += aln((size_t)N * CH * 2);
    float* pooled = (float*)p; p += aln((size_t)n_graphs * CH * 4);
    unsigned short* wt[6];
    for (int i = 0; i < 6; ++i) { wt[i] = (unsigned short*)p; p += aln((size_t)CH * CH * 2); }
    (void)ws_size; (void)n_in;

    // zero bucket counters + pooled accumulator up front
    hipMemsetAsync(bucketCnt, 0, NB * 4, stream);
    hipMemsetAsync(pooled, 0, (size_t)n_graphs * CH * 4, stream);

    // prep: convert x + fragment-swizzle weights, one dispatch
    int n4 = N * CH / 4;
    int nConvBlk = (n4 + 255) / 256;
    WPtrs wp;
    for (int l = 0; l < 3; ++l) {
        wp.s[2 * l] = w1[l];     wp.d[2 * l] = wt[2 * l];
        wp.s[2 * l + 1] = w2[l]; wp.d[2 * l + 1] = wt[2 * l + 1];
    }
    prep_kernel<<<nConvBlk + 384, 256, 0, stream>>>((const float4*)x, (uint2*)xb, n4, nConvBlk, wp);

    // CSR build
    partition_kernel<<<(E + PCHUNK - 1) / PCHUNK, 256, 0, stream>>>(src, dst, bucketCnt, pairs, E);
    build_csr_kernel<<<NB, 256, 0, stream>>>(pairs, bucketCnt, offs, csr, N);

    int ablk = (N + 15) / 16;
    int mblk = (N + BM - 1) / BM;

    // layer 0
    aggregate_kernel<0><<<ablk, 256, 0, stream>>>((const uint4*)xb, offs, csr, (uint4*)zb, N);
    mlp_mfma_kernel<0, 1, 0><<<mblk, 512, 0, stream>>>(zb, wt[0], b1[0], wt[1], b2[0], hA, batch, pooled, N);
    // layer 1
    aggregate_kernel<1><<<ablk, 256, 0, stream>>>((const uint4*)hA, offs, csr, (uint4*)zb, N);
    mlp_mfma_kernel<1, 1, 0><<<mblk, 512, 0, stream>>>(zb, wt[2], b1[1], wt[3], b2[1], hB, batch, pooled, N);
    // layer 2 (+ fused pooling epilogue)
    aggregate_kernel<2><<<ablk, 256, 0, stream>>>((const uint4*)hB, offs, csr, (uint4*)zb, N);
    mlp_mfma_kernel<2, 0, 1><<<mblk, 512, 0, stream>>>(zb, wt[4], b1[2], wt[5], b2[2], hA, batch, pooled, N);

    final_linear_kernel<<<n_graphs, CH, 0, stream>>>(pooled, lin_w, lin_b, out);
}

// Round 10
// 412.215 us; speedup vs baseline: 1.5177x; 1.0560x over previous
//
#include <hip/hip_runtime.h>

#define CH 128
#define OUTC 10
#define NB 256            // buckets (dst >> 9), only ceil(N/512) used
#define BCAP 10240        // per-bucket pair capacity (avg ~8192, >22 sigma margin)
#define PCHUNK 2048       // edges per partition block

typedef __attribute__((ext_vector_type(8))) short short8;
typedef __attribute__((ext_vector_type(4))) short short4v;
typedef __attribute__((ext_vector_type(16))) float f32x16;

// ---------------------------------------------------------------- helpers

__device__ inline unsigned short f2bf(float f) {
    unsigned u = __builtin_bit_cast(unsigned, f);
    u += 0x7fffu + ((u >> 16) & 1u);   // RNE
    return (unsigned short)(u >> 16);
}
__device__ inline float bflo(unsigned u) { return __builtin_bit_cast(float, u << 16); }
__device__ inline float bfhi(unsigned u) { return __builtin_bit_cast(float, u & 0xffff0000u); }

__device__ inline void acc8(float* a, const uint4& v) {
    a[0] += bflo(v.x); a[1] += bfhi(v.x);
    a[2] += bflo(v.y); a[3] += bfhi(v.y);
    a[4] += bflo(v.z); a[5] += bfhi(v.z);
    a[6] += bflo(v.w); a[7] += bfhi(v.w);
}

// ---------------------------------------------------------------- prep: x->bf16, w->frag-swizzle, zero bucketCnt+pooled
// wsw element i (per matrix): j=i&7, l=(i>>3)&63, k0=(i>>9)&7, ct=(i>>12)&3
// stores w[(k0*16 + (l>>5)*8 + j)*128 + ct*32 + (l&31)]  (B-frag load = wave-contiguous)

struct WPtrs { const float* s[6]; unsigned short* d[6]; };

__global__ void prep_kernel(const float4* __restrict__ x4, uint2* __restrict__ xb, int n4,
                            int nConvBlk, WPtrs p, int* __restrict__ bucketCnt,
                            uint4* __restrict__ pooled4, int nPooled4) {
    int tid = threadIdx.x;
    int b = blockIdx.x;
    if (b < nConvBlk) {
        int i = b * 256 + tid;
        if (i < n4) {
            float4 v = x4[i];
            uint2 o;
            o.x = (unsigned)f2bf(v.x) | ((unsigned)f2bf(v.y) << 16);
            o.y = (unsigned)f2bf(v.z) | ((unsigned)f2bf(v.w) << 16);
            xb[i] = o;
        }
    } else if (b < nConvBlk + 384) {
        int bb = b - nConvBlk;            // 0..383
        int m = bb >> 6;                  // matrix 0..5
        int i = (bb & 63) * 256 + tid;    // 0..16383
        int j = i & 7;
        int l = (i >> 3) & 63;
        int k0 = (i >> 9) & 7;
        int ct = (i >> 12) & 3;
        int k = k0 * 16 + ((l >> 5) << 3) + j;
        int nn = ct * 32 + (l & 31);
        p.d[m][i] = f2bf(p.s[m][k * CH + nn]);
    } else if (b == nConvBlk + 384) {
        bucketCnt[tid] = 0;
    } else {
        int i = (b - nConvBlk - 385) * 256 + tid;
        if (i < nPooled4) pooled4[i] = make_uint4(0, 0, 0, 0);
    }
}

// ---------------------------------------------------------------- CSR build, phase 1: partition edges into buckets

__global__ void partition_kernel(const int* __restrict__ src, const int* __restrict__ dst,
                                 int* __restrict__ bucketCnt, unsigned* __restrict__ pairs, int E) {
    __shared__ int hist[NB];
    __shared__ int base[NB];
    __shared__ int cur[NB];
    int tid = threadIdx.x;       // 256
    int e0 = blockIdx.x * PCHUNK;

    hist[tid] = 0;
    __syncthreads();
    #pragma unroll
    for (int i = 0; i < PCHUNK / 256; ++i) {
        int e = e0 + tid + i * 256;
        if (e < E) atomicAdd(&hist[dst[e] >> 9], 1);
    }
    __syncthreads();
    {
        int c = hist[tid];
        base[tid] = (c > 0) ? atomicAdd(&bucketCnt[tid], c) : 0;
        cur[tid] = 0;
    }
    __syncthreads();
    #pragma unroll
    for (int i = 0; i < PCHUNK / 256; ++i) {
        int e = e0 + tid + i * 256;
        if (e < E) {
            int d = dst[e];
            int bkt = d >> 9;
            int p = base[bkt] + atomicAdd(&cur[bkt], 1);
            if (p < BCAP)
                pairs[bkt * BCAP + p] = ((unsigned)(d & 511) << 17) | (unsigned)src[e];
        }
    }
}

// ---------------------------------------------------------------- CSR build, phase 2 (self-scans bucket counts)

__launch_bounds__(256)
__global__ void build_csr_kernel(const unsigned* __restrict__ pairs, const int* __restrict__ bucketCnt,
                                 int* __restrict__ offs, int* __restrict__ csr, int N) {
    __shared__ int bsm[NB];
    __shared__ int ldeg[512];
    __shared__ int s0[512], s1[512];
    __shared__ int lexc[512];
    __shared__ int lcur[512];
    __shared__ int lcsr[BCAP];

    int b = blockIdx.x;
    int node0 = b << 9;
    if (node0 >= N) return;
    int nLocal = min(512, N - node0);
    int tid = threadIdx.x;   // 256

    bsm[tid] = bucketCnt[tid];
    __syncthreads();
    for (int off = 1; off < NB; off <<= 1) {
        int t = (tid >= off) ? bsm[tid - off] : 0;
        __syncthreads();
        bsm[tid] += t;
        __syncthreads();
    }
    int cnt = min(bucketCnt[b], BCAP);
    int gbase = bsm[b] - bucketCnt[b];

    for (int i = tid; i < 512; i += 256) ldeg[i] = 0;
    __syncthreads();
    for (int i = tid; i < cnt; i += 256)
        atomicAdd(&ldeg[pairs[b * BCAP + i] >> 17], 1);
    __syncthreads();

    for (int i = tid; i < 512; i += 256) s0[i] = ldeg[i];
    __syncthreads();
    int* sp = s0; int* dp = s1;
    for (int off = 1; off < 512; off <<= 1) {
        for (int i = tid; i < 512; i += 256)
            dp[i] = sp[i] + ((i >= off) ? sp[i - off] : 0);
        __syncthreads();
        int* t = sp; sp = dp; dp = t;
    }
    for (int i = tid; i < 512; i += 256) {
        int ex = sp[i] - ldeg[i];
        lexc[i] = ex;
        lcur[i] = ex;
    }
    __syncthreads();

    for (int i = tid; i < cnt; i += 256) {
        unsigned w = pairs[b * BCAP + i];
        int ppos = atomicAdd(&lcur[w >> 17], 1);
        lcsr[ppos] = (int)(w & 0x1ffffu);
    }
    __syncthreads();

    for (int i = tid; i < cnt; i += 256) csr[gbase + i] = lcsr[i];
    for (int i = tid; i < nLocal; i += 256) offs[node0 + i] = gbase + lexc[i];
    if (tid == 0 && node0 + nLocal == N) offs[N] = gbase + cnt;
}

// ---------------------------------------------------------------- aggregation (bf16, 4-edge unroll — known-good form)

template <int L>
__global__ void aggregate_kernel(const uint4* __restrict__ h4, const int* __restrict__ offs,
                                 const int* __restrict__ csr, uint4* __restrict__ z4, int n) {
    int node = blockIdx.x * 16 + (threadIdx.x >> 4);
    int lane = threadIdx.x & 15;
    if (node >= n) return;
    int beg = offs[node], end = offs[node + 1];

    float a[8];
    {
        uint4 self = h4[node * 16 + lane];
        a[0] = bflo(self.x); a[1] = bfhi(self.x);
        a[2] = bflo(self.y); a[3] = bfhi(self.y);
        a[4] = bflo(self.z); a[5] = bfhi(self.z);
        a[6] = bflo(self.w); a[7] = bfhi(self.w);
    }
    int e = beg;
    for (; e + 4 <= end; e += 4) {
        int s0 = csr[e], s1 = csr[e + 1], s2 = csr[e + 2], s3 = csr[e + 3];
        uint4 v0 = h4[s0 * 16 + lane];
        uint4 v1 = h4[s1 * 16 + lane];
        uint4 v2 = h4[s2 * 16 + lane];
        uint4 v3 = h4[s3 * 16 + lane];
        acc8(a, v0); acc8(a, v1); acc8(a, v2); acc8(a, v3);
    }
    for (; e < end; ++e) {
        uint4 v = h4[csr[e] * 16 + lane];
        acc8(a, v);
    }
    uint4 o;
    o.x = (unsigned)f2bf(a[0]) | ((unsigned)f2bf(a[1]) << 16);
    o.y = (unsigned)f2bf(a[2]) | ((unsigned)f2bf(a[3]) << 16);
    o.z = (unsigned)f2bf(a[4]) | ((unsigned)f2bf(a[5]) << 16);
    o.w = (unsigned)f2bf(a[6]) | ((unsigned)f2bf(a[7]) << 16);
    z4[node * 16 + lane] = o;
}

#define PQ2 132

// ---------------------------------------------------------------- MFMA MLP v3 (layers 0, 2): 32x32x16, swizzled-global B

#define BM 128

template <int L, int RELU, int POOL>
__launch_bounds__(512)
__global__ void mlp_mfma_kernel(const unsigned short* __restrict__ z,
                                const unsigned short* __restrict__ w1s, const float* __restrict__ b1,
                                const unsigned short* __restrict__ w2s, const float* __restrict__ b2,
                                unsigned short* __restrict__ hout,
                                const int* __restrict__ batch, float* __restrict__ pooled,
                                int n) {
    __shared__ __align__(16) unsigned short zs[BM * PQ2];   // 33.8 KB

    int tid = threadIdx.x;
    int row0 = blockIdx.x * BM;
    int wv = tid >> 6;         // 0..7
    int lane = tid & 63;
    int l31 = lane & 31;
    int kh = lane >> 5;        // 0..1
    int rt = wv & 3;           // row tile (32 rows)
    int ch = wv >> 2;          // col half (64 cols)
    int ct0 = ch * 2;
    int arow = rt * 32 + l31;

    for (int i = tid; i < BM * 16; i += 512) {
        int r = i >> 4, c = i & 15;
        int row = row0 + r;
        uint4 v = (row < n) ? ((const uint4*)z)[row * 16 + c] : make_uint4(0, 0, 0, 0);
        *(uint2*)&zs[r * PQ2 + c * 8]     = make_uint2(v.x, v.y);
        *(uint2*)&zs[r * PQ2 + c * 8 + 4] = make_uint2(v.z, v.w);
    }
    __syncthreads();

    f32x16 acc0, acc1;
    {
        float bv0 = b1[ct0 * 32 + l31];
        float bv1 = b1[(ct0 + 1) * 32 + l31];
        #pragma unroll
        for (int r = 0; r < 16; ++r) { acc0[r] = bv0; acc1[r] = bv1; }
    }
    #pragma unroll
    for (int k0 = 0; k0 < 8; ++k0) {
        short8 afr;
        {
            short4v lo = *(const short4v*)&zs[arow * PQ2 + k0 * 16 + kh * 8];
            short4v hi = *(const short4v*)&zs[arow * PQ2 + k0 * 16 + kh * 8 + 4];
            afr = (short8){lo[0], lo[1], lo[2], lo[3], hi[0], hi[1], hi[2], hi[3]};
        }
        short8 bf0 = *(const short8*)&w1s[(((ct0 * 8 + k0) * 64) + lane) * 8];
        short8 bf1 = *(const short8*)&w1s[((((ct0 + 1) * 8 + k0) * 64) + lane) * 8];
        acc0 = __builtin_amdgcn_mfma_f32_32x32x16_bf16(afr, bf0, acc0, 0, 0, 0);
        acc1 = __builtin_amdgcn_mfma_f32_32x32x16_bf16(afr, bf1, acc1, 0, 0, 0);
    }
    __syncthreads();

    #pragma unroll
    for (int reg = 0; reg < 16; ++reg) {
        int crow = (reg & 3) + 8 * (reg >> 2) + 4 * kh;
        zs[(rt * 32 + crow) * PQ2 + ch * 64 + l31]      = f2bf(fmaxf(acc0[reg], 0.f));
        zs[(rt * 32 + crow) * PQ2 + ch * 64 + 32 + l31] = f2bf(fmaxf(acc1[reg], 0.f));
    }
    __syncthreads();

    {
        float bv0 = b2[ct0 * 32 + l31];
        float bv1 = b2[(ct0 + 1) * 32 + l31];
        #pragma unroll
        for (int r = 0; r < 16; ++r) { acc0[r] = bv0; acc1[r] = bv1; }
    }
    #pragma unroll
    for (int k0 = 0; k0 < 8; ++k0) {
        short8 afr;
        {
            short4v lo = *(const short4v*)&zs[arow * PQ2 + k0 * 16 + kh * 8];
            short4v hi = *(const short4v*)&zs[arow * PQ2 + k0 * 16 + kh * 8 + 4];
            afr = (short8){lo[0], lo[1], lo[2], lo[3], hi[0], hi[1], hi[2], hi[3]};
        }
        short8 bf0 = *(const short8*)&w2s[(((ct0 * 8 + k0) * 64) + lane) * 8];
        short8 bf1 = *(const short8*)&w2s[((((ct0 + 1) * 8 + k0) * 64) + lane) * 8];
        acc0 = __builtin_amdgcn_mfma_f32_32x32x16_bf16(afr, bf0, acc0, 0, 0, 0);
        acc1 = __builtin_amdgcn_mfma_f32_32x32x16_bf16(afr, bf1, acc1, 0, 0, 0);
    }
    __syncthreads();

    #pragma unroll
    for (int reg = 0; reg < 16; ++reg) {
        int crow = (reg & 3) + 8 * (reg >> 2) + 4 * kh;
        float v0 = acc0[reg], v1 = acc1[reg];
        if (RELU) { v0 = fmaxf(v0, 0.f); v1 = fmaxf(v1, 0.f); }
        zs[(rt * 32 + crow) * PQ2 + ch * 64 + l31]      = f2bf(v0);
        zs[(rt * 32 + crow) * PQ2 + ch * 64 + 32 + l31] = f2bf(v1);
    }
    __syncthreads();

    if (!POOL) {
        for (int i = tid; i < BM * 16; i += 512) {
            int r = i >> 4, c = i & 15;
            int row = row0 + r;
            if (row < n) {
                uint2 a = *(const uint2*)&zs[r * PQ2 + c * 8];
                uint2 b = *(const uint2*)&zs[r * PQ2 + c * 8 + 4];
                ((uint4*)hout)[row * 16 + c] = make_uint4(a.x, a.y, b.x, b.y);
            }
        }
    } else {
        int c2 = tid & 63;
        int rs = tid >> 6;
        float a0 = 0.f, a1 = 0.f;
        int prevg = -1;
        #pragma unroll
        for (int i = 0; i < BM / 8; ++i) {
            int r = rs + 8 * i;
            int row = row0 + r;
            if (row >= n) break;
            int g = batch[row];
            if (g != prevg) {
                if (prevg >= 0) {
                    atomicAdd(&pooled[prevg * CH + 2 * c2], a0);
                    atomicAdd(&pooled[prevg * CH + 2 * c2 + 1], a1);
                }
                prevg = g; a0 = 0.f; a1 = 0.f;
            }
            unsigned v = *(const unsigned*)&zs[r * PQ2 + c2 * 2];
            a0 += bflo(v); a1 += bfhi(v);
        }
        if (prevg >= 0) {
            atomicAdd(&pooled[prevg * CH + 2 * c2], a0);
            atomicAdd(&pooled[prevg * CH + 2 * c2 + 1], a1);
        }
    }
}

// ---------------------------------------------------------------- fused GIN layer v2 (layer 1 only — A/B experiment):
// gather straight into LDS, then MFMA. BM=64, 512 threads, 16.9 KB LDS,
// one 32x32 tile per wave (acc = 16 VGPR — occupancy-friendly).

#define FBM 64

template <int RELU>
__launch_bounds__(512)
__global__ void fused_gin_kernel(const uint4* __restrict__ h4,
                                 const int* __restrict__ offs, const int* __restrict__ csr,
                                 const unsigned short* __restrict__ w1s, const float* __restrict__ b1,
                                 const unsigned short* __restrict__ w2s, const float* __restrict__ b2,
                                 unsigned short* __restrict__ hout, int n) {
    __shared__ __align__(16) unsigned short zs[FBM * PQ2];   // 16.9 KB

    int tid = threadIdx.x;
    int row0 = blockIdx.x * FBM;

    // ---- gather phase (identical accumulation order to aggregate_kernel)
    {
        int gl = tid & 15;
        int grp = tid >> 4;    // 0..31
        #pragma unroll
        for (int it = 0; it < 2; ++it) {
            int rr = grp + 32 * it;
            int node = row0 + rr;
            unsigned o0 = 0, o1 = 0, o2 = 0, o3 = 0;
            if (node < n) {
                int beg = offs[node], end = offs[node + 1];
                float a[8];
                uint4 self = h4[node * 16 + gl];
                a[0] = bflo(self.x); a[1] = bfhi(self.x);
                a[2] = bflo(self.y); a[3] = bfhi(self.y);
                a[4] = bflo(self.z); a[5] = bfhi(self.z);
                a[6] = bflo(self.w); a[7] = bfhi(self.w);
                int e = beg;
                for (; e + 4 <= end; e += 4) {
                    int s0 = csr[e], s1 = csr[e + 1], s2 = csr[e + 2], s3 = csr[e + 3];
                    uint4 v0 = h4[s0 * 16 + gl];
                    uint4 v1 = h4[s1 * 16 + gl];
                    uint4 v2 = h4[s2 * 16 + gl];
                    uint4 v3 = h4[s3 * 16 + gl];
                    acc8(a, v0); acc8(a, v1); acc8(a, v2); acc8(a, v3);
                }
                for (; e < end; ++e) {
                    uint4 v = h4[csr[e] * 16 + gl];
                    acc8(a, v);
                }
                o0 = (unsigned)f2bf(a[0]) | ((unsigned)f2bf(a[1]) << 16);
                o1 = (unsigned)f2bf(a[2]) | ((unsigned)f2bf(a[3]) << 16);
                o2 = (unsigned)f2bf(a[4]) | ((unsigned)f2bf(a[5]) << 16);
                o3 = (unsigned)f2bf(a[6]) | ((unsigned)f2bf(a[7]) << 16);
            }
            *(uint2*)&zs[rr * PQ2 + gl * 8]     = make_uint2(o0, o1);
            *(uint2*)&zs[rr * PQ2 + gl * 8 + 4] = make_uint2(o2, o3);
        }
    }
    __syncthreads();

    int wv = tid >> 6;         // 0..7
    int lane = tid & 63;
    int l31 = lane & 31;
    int kh = lane >> 5;
    int rt = wv & 1;           // 2 row tiles of 32
    int ct = wv >> 1;          // 4 col tiles of 32
    int arow = rt * 32 + l31;

    // ---- matmul 1
    f32x16 acc;
    {
        float bv = b1[ct * 32 + l31];
        #pragma unroll
        for (int r = 0; r < 16; ++r) acc[r] = bv;
    }
    #pragma unroll
    for (int k0 = 0; k0 < 8; ++k0) {
        short8 afr;
        {
            short4v lo = *(const short4v*)&zs[arow * PQ2 + k0 * 16 + kh * 8];
            short4v hi = *(const short4v*)&zs[arow * PQ2 + k0 * 16 + kh * 8 + 4];
            afr = (short8){lo[0], lo[1], lo[2], lo[3], hi[0], hi[1], hi[2], hi[3]};
        }
        short8 bfr = *(const short8*)&w1s[(((ct * 8 + k0) * 64) + lane) * 8];
        acc = __builtin_amdgcn_mfma_f32_32x32x16_bf16(afr, bfr, acc, 0, 0, 0);
    }
    __syncthreads();

    #pragma unroll
    for (int reg = 0; reg < 16; ++reg) {
        int crow = (reg & 3) + 8 * (reg >> 2) + 4 * kh;
        zs[(rt * 32 + crow) * PQ2 + ct * 32 + l31] = f2bf(fmaxf(acc[reg], 0.f));
    }
    __syncthreads();

    // ---- matmul 2
    {
        float bv = b2[ct * 32 + l31];
        #pragma unroll
        for (int r = 0; r < 16; ++r) acc[r] = bv;
    }
    #pragma unroll
    for (int k0 = 0; k0 < 8; ++k0) {
        short8 afr;
        {
            short4v lo = *(const short4v*)&zs[arow * PQ2 + k0 * 16 + kh * 8];
            short4v hi = *(const short4v*)&zs[arow * PQ2 + k0 * 16 + kh * 8 + 4];
            afr = (short8){lo[0], lo[1], lo[2], lo[3], hi[0], hi[1], hi[2], hi[3]};
        }
        short8 bfr = *(const short8*)&w2s[(((ct * 8 + k0) * 64) + lane) * 8];
        acc = __builtin_amdgcn_mfma_f32_32x32x16_bf16(afr, bfr, acc, 0, 0, 0);
    }
    __syncthreads();

    #pragma unroll
    for (int reg = 0; reg < 16; ++reg) {
        int crow = (reg & 3) + 8 * (reg >> 2) + 4 * kh;
        float v = acc[reg];
        if (RELU) v = fmaxf(v, 0.f);
        zs[(rt * 32 + crow) * PQ2 + ct * 32 + l31] = f2bf(v);
    }
    __syncthreads();

    for (int i = tid; i < FBM * 16; i += 512) {
        int r = i >> 4, c = i & 15;
        int row = row0 + r;
        if (row < n) {
            uint2 a = *(const uint2*)&zs[r * PQ2 + c * 8];
            uint2 b = *(const uint2*)&zs[r * PQ2 + c * 8 + 4];
            ((uint4*)hout)[row * 16 + c] = make_uint4(a.x, a.y, b.x, b.y);
        }
    }
}

// ---------------------------------------------------------------- final linear

__global__ void final_linear_kernel(const float* __restrict__ pooled, const float* __restrict__ lin_w,
                                    const float* __restrict__ lin_b, float* __restrict__ out) {
    int g = blockIdx.x;
    int tid = threadIdx.x;   // 128
    __shared__ float pl[CH];
    pl[tid] = pooled[g * CH + tid];
    __syncthreads();
    if (tid < OUTC) {
        float a = lin_b[tid];
        #pragma unroll 16
        for (int c = 0; c < CH; ++c) a = fmaf(pl[c], lin_w[c * OUTC + tid], a);
        out[g * OUTC + tid] = a;
    }
}

// ---------------------------------------------------------------- launch

static inline size_t aln(size_t x) { return (x + 255) & ~size_t(255); }

extern "C" void kernel_launch(void* const* d_in, const int* in_sizes, int n_in,
                              void* d_out, int out_size, void* d_ws, size_t ws_size,
                              hipStream_t stream) {
    const float* x      = (const float*)d_in[0];
    const int*   ei     = (const int*)d_in[1];
    const int*   batch  = (const int*)d_in[2];
    const float* w1[3]  = {(const float*)d_in[3], (const float*)d_in[7],  (const float*)d_in[11]};
    const float* b1[3]  = {(const float*)d_in[4], (const float*)d_in[8],  (const float*)d_in[12]};
    const float* w2[3]  = {(const float*)d_in[5], (const float*)d_in[9],  (const float*)d_in[13]};
    const float* b2[3]  = {(const float*)d_in[6], (const float*)d_in[10], (const float*)d_in[14]};
    const float* lin_w  = (const float*)d_in[15];
    const float* lin_b  = (const float*)d_in[16];
    float* out = (float*)d_out;

    int E = in_sizes[1] / 2;
    int N = in_sizes[2];
    int n_graphs = out_size / OUTC;
    const int* src = ei;
    const int* dst = ei + E;

    char* p = (char*)d_ws;
    int* bucketCnt  = (int*)p; p += aln(NB * 4);
    unsigned* pairs = (unsigned*)p; p += aln((size_t)NB * BCAP * 4);
    int* offs       = (int*)p; p += aln((size_t)(N + 1) * 4);
    int* csr        = (int*)p; p += aln((size_t)E * 4);
    unsigned short* xb = (unsigned short*)p; p += aln((size_t)N * CH * 2);
    unsigned short* zb = (unsigned short*)p; p += aln((size_t)N * CH * 2);
    unsigned short* hA = (unsigned short*)p; p += aln((size_t)N * CH * 2);
    unsigned short* hB = (unsigned short*)p; p += aln((size_t)N * CH * 2);
    float* pooled = (float*)p; p += aln((size_t)n_graphs * CH * 4);
    unsigned short* wt[6];
    for (int i = 0; i < 6; ++i) { wt[i] = (unsigned short*)p; p += aln((size_t)CH * CH * 2); }
    (void)ws_size; (void)n_in;

    // prep: convert x + swizzle weights + zero bucketCnt/pooled, one dispatch
    int n4 = N * CH / 4;
    int nConvBlk = (n4 + 255) / 256;
    int nPooled4 = n_graphs * CH / 4;
    int nZeroBlk = (nPooled4 + 255) / 256;
    WPtrs wp;
    for (int l = 0; l < 3; ++l) {
        wp.s[2 * l] = w1[l];     wp.d[2 * l] = wt[2 * l];
        wp.s[2 * l + 1] = w2[l]; wp.d[2 * l + 1] = wt[2 * l + 1];
    }
    prep_kernel<<<nConvBlk + 384 + 1 + nZeroBlk, 256, 0, stream>>>(
        (const float4*)x, (uint2*)xb, n4, nConvBlk, wp, bucketCnt, (uint4*)pooled, nPooled4);

    // CSR build
    partition_kernel<<<(E + PCHUNK - 1) / PCHUNK, 256, 0, stream>>>(src, dst, bucketCnt, pairs, E);
    build_csr_kernel<<<NB, 256, 0, stream>>>(pairs, bucketCnt, offs, csr, N);

    int ablk = (N + 15) / 16;
    int mblk = (N + BM - 1) / BM;
    int fblk = (N + FBM - 1) / FBM;

    // layer 0 (split — control)
    aggregate_kernel<0><<<ablk, 256, 0, stream>>>((const uint4*)xb, offs, csr, (uint4*)zb, N);
    mlp_mfma_kernel<0, 1, 0><<<mblk, 512, 0, stream>>>(zb, wt[0], b1[0], wt[1], b2[0], hA, batch, pooled, N);
    // layer 1 (fused — experiment)
    fused_gin_kernel<1><<<fblk, 512, 0, stream>>>((const uint4*)hA, offs, csr,
                                                  wt[2], b1[1], wt[3], b2[1], hB, N);
    // layer 2 (split + fused pooling epilogue)
    aggregate_kernel<2><<<ablk, 256, 0, stream>>>((const uint4*)hB, offs, csr, (uint4*)zb, N);
    mlp_mfma_kernel<2, 0, 1><<<mblk, 512, 0, stream>>>(zb, wt[4], b1[2], wt[5], b2[2], hA, batch, pooled, N);

    final_linear_kernel<<<n_graphs, CH, 0, stream>>>(pooled, lin_w, lin_b, out);
}

// Round 11
// 384.661 us; speedup vs baseline: 1.6264x; 1.0716x over previous
//
#include <hip/hip_runtime.h>

#define CH 128
#define OUTC 10
#define NB 256            // buckets (dst >> 9), only ceil(N/512) used
#define BCAP 10240        // per-bucket pair capacity (avg ~8192, >22 sigma margin)
#define PCHUNK 2048       // edges per partition block
#define PQ2 132           // LDS pitch in bf16 (dword stride 66 -> 2-way bank alias = free)
#define FBM 64            // rows per fused-layer block

typedef __attribute__((ext_vector_type(8))) short short8;
typedef __attribute__((ext_vector_type(4))) short short4v;
typedef __attribute__((ext_vector_type(16))) float f32x16;

// ---------------------------------------------------------------- helpers

__device__ inline unsigned short f2bf(float f) {
    unsigned u = __builtin_bit_cast(unsigned, f);
    u += 0x7fffu + ((u >> 16) & 1u);   // RNE
    return (unsigned short)(u >> 16);
}
__device__ inline float bflo(unsigned u) { return __builtin_bit_cast(float, u << 16); }
__device__ inline float bfhi(unsigned u) { return __builtin_bit_cast(float, u & 0xffff0000u); }

__device__ inline void acc8(float* a, const uint4& v) {
    a[0] += bflo(v.x); a[1] += bfhi(v.x);
    a[2] += bflo(v.y); a[3] += bfhi(v.y);
    a[4] += bflo(v.z); a[5] += bfhi(v.z);
    a[6] += bflo(v.w); a[7] += bfhi(v.w);
}

// ---------------------------------------------------------------- mega prep: edge partition + x->bf16 + w-swizzle + pooled zero
// Block ranges (independent work, no cross-range deps):
//   [0, nPartBlk)                 : edge partition (bucketCnt pre-zeroed via memset)
//   [nPartBlk, +nConvBlk)         : x -> bf16
//   [.., +384)                    : weights -> MFMA-frag-swizzled bf16
//   [.., +nZeroBlk)               : zero pooled accumulator

struct WPtrs { const float* s[6]; unsigned short* d[6]; };

__global__ void prep_part_kernel(const int* __restrict__ src, const int* __restrict__ dst,
                                 int* __restrict__ bucketCnt, unsigned* __restrict__ pairs, int E,
                                 int nPartBlk,
                                 const float4* __restrict__ x4, uint2* __restrict__ xb, int n4,
                                 int nConvBlk, WPtrs p,
                                 uint4* __restrict__ pooled4, int nPooled4) {
    __shared__ int hist[NB];
    __shared__ int base[NB];
    __shared__ int cur[NB];
    int tid = threadIdx.x;   // 256
    int b = blockIdx.x;

    if (b < nPartBlk) {
        int e0 = b * PCHUNK;
        hist[tid] = 0;
        __syncthreads();
        #pragma unroll
        for (int i = 0; i < PCHUNK / 256; ++i) {
            int e = e0 + tid + i * 256;
            if (e < E) atomicAdd(&hist[dst[e] >> 9], 1);
        }
        __syncthreads();
        {
            int c = hist[tid];
            base[tid] = (c > 0) ? atomicAdd(&bucketCnt[tid], c) : 0;
            cur[tid] = 0;
        }
        __syncthreads();
        #pragma unroll
        for (int i = 0; i < PCHUNK / 256; ++i) {
            int e = e0 + tid + i * 256;
            if (e < E) {
                int d = dst[e];
                int bkt = d >> 9;
                int pos = base[bkt] + atomicAdd(&cur[bkt], 1);
                if (pos < BCAP)
                    pairs[bkt * BCAP + pos] = ((unsigned)(d & 511) << 17) | (unsigned)src[e];
            }
        }
    } else if (b < nPartBlk + nConvBlk) {
        int i = (b - nPartBlk) * 256 + tid;
        if (i < n4) {
            float4 v = x4[i];
            uint2 o;
            o.x = (unsigned)f2bf(v.x) | ((unsigned)f2bf(v.y) << 16);
            o.y = (unsigned)f2bf(v.z) | ((unsigned)f2bf(v.w) << 16);
            xb[i] = o;
        }
    } else if (b < nPartBlk + nConvBlk + 384) {
        int bb = b - nPartBlk - nConvBlk;  // 0..383
        int m = bb >> 6;                   // matrix 0..5
        int i = (bb & 63) * 256 + tid;     // 0..16383
        int j = i & 7;
        int l = (i >> 3) & 63;
        int k0 = (i >> 9) & 7;
        int ct = (i >> 12) & 3;
        int k = k0 * 16 + ((l >> 5) << 3) + j;
        int nn = ct * 32 + (l & 31);
        p.d[m][i] = f2bf(p.s[m][k * CH + nn]);
    } else {
        int i = (b - nPartBlk - nConvBlk - 384) * 256 + tid;
        if (i < nPooled4) pooled4[i] = make_uint4(0, 0, 0, 0);
    }
}

// ---------------------------------------------------------------- CSR build (self-scans bucket counts)

__launch_bounds__(256)
__global__ void build_csr_kernel(const unsigned* __restrict__ pairs, const int* __restrict__ bucketCnt,
                                 int* __restrict__ offs, int* __restrict__ csr, int N) {
    __shared__ int bsm[NB];
    __shared__ int ldeg[512];
    __shared__ int s0[512], s1[512];
    __shared__ int lexc[512];
    __shared__ int lcur[512];
    __shared__ int lcsr[BCAP];

    int b = blockIdx.x;
    int node0 = b << 9;
    if (node0 >= N) return;
    int nLocal = min(512, N - node0);
    int tid = threadIdx.x;   // 256

    bsm[tid] = bucketCnt[tid];
    __syncthreads();
    for (int off = 1; off < NB; off <<= 1) {
        int t = (tid >= off) ? bsm[tid - off] : 0;
        __syncthreads();
        bsm[tid] += t;
        __syncthreads();
    }
    int cnt = min(bucketCnt[b], BCAP);
    int gbase = bsm[b] - bucketCnt[b];

    for (int i = tid; i < 512; i += 256) ldeg[i] = 0;
    __syncthreads();
    for (int i = tid; i < cnt; i += 256)
        atomicAdd(&ldeg[pairs[b * BCAP + i] >> 17], 1);
    __syncthreads();

    for (int i = tid; i < 512; i += 256) s0[i] = ldeg[i];
    __syncthreads();
    int* sp = s0; int* dp = s1;
    for (int off = 1; off < 512; off <<= 1) {
        for (int i = tid; i < 512; i += 256)
            dp[i] = sp[i] + ((i >= off) ? sp[i - off] : 0);
        __syncthreads();
        int* t = sp; sp = dp; dp = t;
    }
    for (int i = tid; i < 512; i += 256) {
        int ex = sp[i] - ldeg[i];
        lexc[i] = ex;
        lcur[i] = ex;
    }
    __syncthreads();

    for (int i = tid; i < cnt; i += 256) {
        unsigned w = pairs[b * BCAP + i];
        int ppos = atomicAdd(&lcur[w >> 17], 1);
        lcsr[ppos] = (int)(w & 0x1ffffu);
    }
    __syncthreads();

    for (int i = tid; i < cnt; i += 256) csr[gbase + i] = lcsr[i];
    for (int i = tid; i < nLocal; i += 256) offs[node0 + i] = gbase + lexc[i];
    if (tid == 0 && node0 + nLocal == N) offs[N] = gbase + cnt;
}

// ---------------------------------------------------------------- fused GIN layer: gather -> LDS -> MFMA MLP -> write | pool
// BM=64, 512 threads, 16.9 KB LDS, one 32x32 MFMA tile per wave (acc=16 VGPR).
// Gather accumulation order identical to the R6 aggregate (bit-exact).

template <int L, int RELU, int POOL>
__launch_bounds__(512)
__global__ void fused_gin_kernel(const uint4* __restrict__ h4,
                                 const int* __restrict__ offs, const int* __restrict__ csr,
                                 const unsigned short* __restrict__ w1s, const float* __restrict__ b1,
                                 const unsigned short* __restrict__ w2s, const float* __restrict__ b2,
                                 unsigned short* __restrict__ hout,
                                 const int* __restrict__ batch, float* __restrict__ pooled,
                                 int n) {
    __shared__ __align__(16) unsigned short zs[FBM * PQ2];   // 16.9 KB

    int tid = threadIdx.x;
    int row0 = blockIdx.x * FBM;

    // ---- gather phase: z = h[node] + sum h[src], fp32 accum -> bf16 into LDS
    {
        int gl = tid & 15;
        int grp = tid >> 4;    // 0..31
        #pragma unroll
        for (int it = 0; it < 2; ++it) {
            int rr = grp + 32 * it;
            int node = row0 + rr;
            unsigned o0 = 0, o1 = 0, o2 = 0, o3 = 0;
            if (node < n) {
                int beg = offs[node], end = offs[node + 1];
                float a[8];
                uint4 self = h4[node * 16 + gl];
                a[0] = bflo(self.x); a[1] = bfhi(self.x);
                a[2] = bflo(self.y); a[3] = bfhi(self.y);
                a[4] = bflo(self.z); a[5] = bfhi(self.z);
                a[6] = bflo(self.w); a[7] = bfhi(self.w);
                int e = beg;
                for (; e + 4 <= end; e += 4) {
                    int s0 = csr[e], s1 = csr[e + 1], s2 = csr[e + 2], s3 = csr[e + 3];
                    uint4 v0 = h4[s0 * 16 + gl];
                    uint4 v1 = h4[s1 * 16 + gl];
                    uint4 v2 = h4[s2 * 16 + gl];
                    uint4 v3 = h4[s3 * 16 + gl];
                    acc8(a, v0); acc8(a, v1); acc8(a, v2); acc8(a, v3);
                }
                for (; e < end; ++e) {
                    uint4 v = h4[csr[e] * 16 + gl];
                    acc8(a, v);
                }
                o0 = (unsigned)f2bf(a[0]) | ((unsigned)f2bf(a[1]) << 16);
                o1 = (unsigned)f2bf(a[2]) | ((unsigned)f2bf(a[3]) << 16);
                o2 = (unsigned)f2bf(a[4]) | ((unsigned)f2bf(a[5]) << 16);
                o3 = (unsigned)f2bf(a[6]) | ((unsigned)f2bf(a[7]) << 16);
            }
            *(uint2*)&zs[rr * PQ2 + gl * 8]     = make_uint2(o0, o1);
            *(uint2*)&zs[rr * PQ2 + gl * 8 + 4] = make_uint2(o2, o3);
        }
    }
    __syncthreads();

    int wv = tid >> 6;         // 0..7
    int lane = tid & 63;
    int l31 = lane & 31;
    int kh = lane >> 5;
    int rt = wv & 1;           // 2 row tiles of 32
    int ct = wv >> 1;          // 4 col tiles of 32
    int arow = rt * 32 + l31;

    // ---- matmul 1: t = relu(z @ w1 + b1)
    f32x16 acc;
    {
        float bv = b1[ct * 32 + l31];
        #pragma unroll
        for (int r = 0; r < 16; ++r) acc[r] = bv;
    }
    #pragma unroll
    for (int k0 = 0; k0 < 8; ++k0) {
        short8 afr;
        {
            short4v lo = *(const short4v*)&zs[arow * PQ2 + k0 * 16 + kh * 8];
            short4v hi = *(const short4v*)&zs[arow * PQ2 + k0 * 16 + kh * 8 + 4];
            afr = (short8){lo[0], lo[1], lo[2], lo[3], hi[0], hi[1], hi[2], hi[3]};
        }
        short8 bfr = *(const short8*)&w1s[(((ct * 8 + k0) * 64) + lane) * 8];
        acc = __builtin_amdgcn_mfma_f32_32x32x16_bf16(afr, bfr, acc, 0, 0, 0);
    }
    __syncthreads();

    #pragma unroll
    for (int reg = 0; reg < 16; ++reg) {
        int crow = (reg & 3) + 8 * (reg >> 2) + 4 * kh;
        zs[(rt * 32 + crow) * PQ2 + ct * 32 + l31] = f2bf(fmaxf(acc[reg], 0.f));
    }
    __syncthreads();

    // ---- matmul 2: h = t @ w2 + b2 [+ relu]
    {
        float bv = b2[ct * 32 + l31];
        #pragma unroll
        for (int r = 0; r < 16; ++r) acc[r] = bv;
    }
    #pragma unroll
    for (int k0 = 0; k0 < 8; ++k0) {
        short8 afr;
        {
            short4v lo = *(const short4v*)&zs[arow * PQ2 + k0 * 16 + kh * 8];
            short4v hi = *(const short4v*)&zs[arow * PQ2 + k0 * 16 + kh * 8 + 4];
            afr = (short8){lo[0], lo[1], lo[2], lo[3], hi[0], hi[1], hi[2], hi[3]};
        }
        short8 bfr = *(const short8*)&w2s[(((ct * 8 + k0) * 64) + lane) * 8];
        acc = __builtin_amdgcn_mfma_f32_32x32x16_bf16(afr, bfr, acc, 0, 0, 0);
    }
    __syncthreads();

    #pragma unroll
    for (int reg = 0; reg < 16; ++reg) {
        int crow = (reg & 3) + 8 * (reg >> 2) + 4 * kh;
        float v = acc[reg];
        if (RELU) v = fmaxf(v, 0.f);
        zs[(rt * 32 + crow) * PQ2 + ct * 32 + l31] = f2bf(v);
    }
    __syncthreads();

    if (!POOL) {
        for (int i = tid; i < FBM * 16; i += 512) {
            int r = i >> 4, c = i & 15;
            int row = row0 + r;
            if (row < n) {
                uint2 a = *(const uint2*)&zs[r * PQ2 + c * 8];
                uint2 b = *(const uint2*)&zs[r * PQ2 + c * 8 + 4];
                ((uint4*)hout)[row * 16 + c] = make_uint4(a.x, a.y, b.x, b.y);
            }
        }
    } else {
        // pool epilogue from LDS tile (batch sorted)
        int c2 = tid & 63;      // uint column (ch 2*c2, 2*c2+1)
        int rs = tid >> 6;      // 0..7
        float a0 = 0.f, a1 = 0.f;
        int prevg = -1;
        #pragma unroll
        for (int i = 0; i < FBM / 8; ++i) {
            int r = rs + 8 * i;
            int row = row0 + r;
            if (row >= n) break;
            int g = batch[row];
            if (g != prevg) {
                if (prevg >= 0) {
                    atomicAdd(&pooled[prevg * CH + 2 * c2], a0);
                    atomicAdd(&pooled[prevg * CH + 2 * c2 + 1], a1);
                }
                prevg = g; a0 = 0.f; a1 = 0.f;
            }
            unsigned v = *(const unsigned*)&zs[r * PQ2 + c2 * 2];
            a0 += bflo(v); a1 += bfhi(v);
        }
        if (prevg >= 0) {
            atomicAdd(&pooled[prevg * CH + 2 * c2], a0);
            atomicAdd(&pooled[prevg * CH + 2 * c2 + 1], a1);
        }
    }
}

// ---------------------------------------------------------------- final linear

__global__ void final_linear_kernel(const float* __restrict__ pooled, const float* __restrict__ lin_w,
                                    const float* __restrict__ lin_b, float* __restrict__ out) {
    int g = blockIdx.x;
    int tid = threadIdx.x;   // 128
    __shared__ float pl[CH];
    pl[tid] = pooled[g * CH + tid];
    __syncthreads();
    if (tid < OUTC) {
        float a = lin_b[tid];
        #pragma unroll 16
        for (int c = 0; c < CH; ++c) a = fmaf(pl[c], lin_w[c * OUTC + tid], a);
        out[g * OUTC + tid] = a;
    }
}

// ---------------------------------------------------------------- launch

static inline size_t aln(size_t x) { return (x + 255) & ~size_t(255); }

extern "C" void kernel_launch(void* const* d_in, const int* in_sizes, int n_in,
                              void* d_out, int out_size, void* d_ws, size_t ws_size,
                              hipStream_t stream) {
    const float* x      = (const float*)d_in[0];
    const int*   ei     = (const int*)d_in[1];
    const int*   batch  = (const int*)d_in[2];
    const float* w1[3]  = {(const float*)d_in[3], (const float*)d_in[7],  (const float*)d_in[11]};
    const float* b1[3]  = {(const float*)d_in[4], (const float*)d_in[8],  (const float*)d_in[12]};
    const float* w2[3]  = {(const float*)d_in[5], (const float*)d_in[9],  (const float*)d_in[13]};
    const float* b2[3]  = {(const float*)d_in[6], (const float*)d_in[10], (const float*)d_in[14]};
    const float* lin_w  = (const float*)d_in[15];
    const float* lin_b  = (const float*)d_in[16];
    float* out = (float*)d_out;

    int E = in_sizes[1] / 2;
    int N = in_sizes[2];
    int n_graphs = out_size / OUTC;
    const int* src = ei;
    const int* dst = ei + E;

    char* p = (char*)d_ws;
    int* bucketCnt  = (int*)p; p += aln(NB * 4);
    unsigned* pairs = (unsigned*)p; p += aln((size_t)NB * BCAP * 4);
    int* offs       = (int*)p; p += aln((size_t)(N + 1) * 4);
    int* csr        = (int*)p; p += aln((size_t)E * 4);
    unsigned short* xb = (unsigned short*)p; p += aln((size_t)N * CH * 2);
    unsigned short* hA = (unsigned short*)p; p += aln((size_t)N * CH * 2);
    unsigned short* hB = (unsigned short*)p; p += aln((size_t)N * CH * 2);
    float* pooled = (float*)p; p += aln((size_t)n_graphs * CH * 4);
    unsigned short* wt[6];
    for (int i = 0; i < 6; ++i) { wt[i] = (unsigned short*)p; p += aln((size_t)CH * CH * 2); }
    (void)ws_size; (void)n_in;

    // bucketCnt must be zero before partition blocks run
    hipMemsetAsync(bucketCnt, 0, NB * 4, stream);

    // mega-prep: partition + convert x + swizzle weights + zero pooled
    int n4 = N * CH / 4;
    int nConvBlk = (n4 + 255) / 256;
    int nPartBlk = (E + PCHUNK - 1) / PCHUNK;
    int nPooled4 = n_graphs * CH / 4;
    int nZeroBlk = (nPooled4 + 255) / 256;
    WPtrs wp;
    for (int l = 0; l < 3; ++l) {
        wp.s[2 * l] = w1[l];     wp.d[2 * l] = wt[2 * l];
        wp.s[2 * l + 1] = w2[l]; wp.d[2 * l + 1] = wt[2 * l + 1];
    }
    prep_part_kernel<<<nPartBlk + nConvBlk + 384 + nZeroBlk, 256, 0, stream>>>(
        src, dst, bucketCnt, pairs, E, nPartBlk,
        (const float4*)x, (uint2*)xb, n4, nConvBlk, wp,
        (uint4*)pooled, nPooled4);

    build_csr_kernel<<<NB, 256, 0, stream>>>(pairs, bucketCnt, offs, csr, N);

    int fblk = (N + FBM - 1) / FBM;

    // three fused GIN layers
    fused_gin_kernel<0, 1, 0><<<fblk, 512, 0, stream>>>((const uint4*)xb, offs, csr,
        wt[0], b1[0], wt[1], b2[0], hA, batch, pooled, N);
    fused_gin_kernel<1, 1, 0><<<fblk, 512, 0, stream>>>((const uint4*)hA, offs, csr,
        wt[2], b1[1], wt[3], b2[1], hB, batch, pooled, N);
    fused_gin_kernel<2, 0, 1><<<fblk, 512, 0, stream>>>((const uint4*)hB, offs, csr,
        wt[4], b1[2], wt[5], b2[2], (unsigned short*)nullptr, batch, pooled, N);

    final_linear_kernel<<<n_graphs, CH, 0, stream>>>(pooled, lin_w, lin_b, out);
}